// Round 21
// baseline (572.795 us; speedup 1.0000x reference)
//
#include <hip/hip_runtime.h>
#include <cstdint>

// ---------------------------------------------------------------------------
// Problem constants
// ---------------------------------------------------------------------------
#define B_    128
#define CIN   1024
#define NPOS  196          // 14*14
#define DM    384
#define NH_   12
#define HD_   32
#define DFF_  1536
#define MT    25088        // B_*NPOS
#define SCALE_Q 0.17677669529663687f   // 1/sqrt(32)
#define SCALE2  0.25503485810335155f   // SCALE_Q * log2(e)  (exp2 domain)

typedef unsigned short u16;
typedef __attribute__((ext_vector_type(8))) short  short8;   // 8 bf16 (4 VGPR)
typedef __attribute__((ext_vector_type(4))) float  f32x4;    // MFMA C/D

__device__ __forceinline__ u16 f2bf(float f) {
  union { float f; uint32_t u; } v; v.f = f;
  uint32_t u = v.u;
  return (u16)((u + 0x7fffu + ((u >> 16) & 1u)) >> 16);
}
__device__ __forceinline__ float bf2f(u16 h) {
  union { uint32_t u; float f; } v; v.u = ((uint32_t)h) << 16;
  return v.f;
}

#define GLDS16(g, l)                                                           \
  __builtin_amdgcn_global_load_lds(                                            \
      (const __attribute__((address_space(1))) void*)(g),                      \
      (__attribute__((address_space(3))) void*)(l), 16, 0, 0)

// ---------------------------------------------------------------------------
// Generic bf16 MFMA GEMM (r20: triple-buffer, 1 barrier/K-step; GLDS with
// pre-swizzled source; counted vmcnt; XCD-chunked bijective swizzle).
// MODE: 0 = bias+relu6 -> bf16 | 1 = bias -> f32 | 2 = plain -> bf16
//       3 = bias+res -> f32    | 4 = split-K partial -> f32
// ---------------------------------------------------------------------------
template <int MODE>
__global__ __launch_bounds__(256) void gemm_k(
    const u16* __restrict__ A, const void* __restrict__ Wv,
    const float* __restrict__ bias, const float* __restrict__ res,
    void* __restrict__ outp,
    int M, int N, int K, int lda, int ldw, int nTN, int splitK)
{
  __shared__ __align__(16) u16 As[3][128 * 32];   // row-major [r][kphys]
  __shared__ __align__(16) u16 Bs[3][128 * 32];

  int nwg = gridDim.x;
  int bid0 = blockIdx.x;
  int qq = nwg >> 3, rr = nwg & 7;
  int xcd = bid0 & 7, idx = bid0 >> 3;
  int bid = (xcd < rr ? xcd * (qq + 1) : rr * (qq + 1) + (xcd - rr) * qq) + idx;

  int split = 0, mT, nT;
  if (MODE == 4) { split = bid / nTN; nT = bid % nTN; mT = 0; }
  else           { mT = bid / nTN;    nT = bid % nTN; }

  const u16* Ab = A + (size_t)split * splitK;
  float* outF = (float*)outp + ((MODE == 4) ? (size_t)split * (size_t)M * N : (size_t)0);
  u16*   outU = (u16*)outp;

  int tid = threadIdx.x;
  int wv = tid >> 6, ln = tid & 63;
  int q = ln >> 4, c = ln & 15;
  int wr = wv >> 1, wc = wv & 1;
  int mBase = mT * 128, nBase = nT * 128;

  f32x4 acc[4][4];
#pragma unroll
  for (int i = 0; i < 4; i++)
#pragma unroll
    for (int j = 0; j < 4; j++) acc[i][j] = (f32x4){0.f, 0.f, 0.f, 0.f};

  const u16* Ag = Ab + (size_t)mBase * lda;
  const u16*  Wg16 = (const u16*)Wv + (size_t)split * splitK + (size_t)nBase * ldw;
  const float* Wg32 = (const float*)Wv + (size_t)split * splitK + (size_t)nBase * ldw;

  int sl = ln & 3, rsub = ln >> 2;          // lane -> (phys kslot, row-in-16)
  int lk = sl ^ ((rsub >> 1) & 3);          // logical kslot this lane fetches

  float4 rbf[2][2];                         // MODE 4: raw f32 W held in regs

  auto STAGE = [&](int t, int buf) {
    int k0 = t * 32;
#pragma unroll
    for (int i = 0; i < 2; i++) {
      int rb = wv * 32 + i * 16;            // wave-uniform row base
      GLDS16(Ag + (size_t)(rb + rsub) * lda + k0 + lk * 8, &As[buf][rb * 32]);
      if constexpr (MODE != 4)
        GLDS16(Wg16 + (size_t)(rb + rsub) * ldw + k0 + lk * 8, &Bs[buf][rb * 32]);
    }
  };
  auto LOADW = [&](int t) {                 // MODE 4: coalesced f32 W load
    int k0 = t * 32;
#pragma unroll
    for (int i = 0; i < 2; i++) {
      const float* wp = Wg32 + (size_t)(wv * 32 + i * 16 + rsub) * ldw + k0 + sl * 8;
      rbf[i][0] = *(const float4*)wp;
      rbf[i][1] = *(const float4*)(wp + 4);
    }
  };
  auto WRITEW = [&](int buf) {              // MODE 4: write to swz layout
#pragma unroll
    for (int i = 0; i < 2; i++) {
      int rloc = wv * 32 + i * 16 + rsub;
      short8 pk;
      pk[0] = (short)f2bf(rbf[i][0].x); pk[1] = (short)f2bf(rbf[i][0].y);
      pk[2] = (short)f2bf(rbf[i][0].z); pk[3] = (short)f2bf(rbf[i][0].w);
      pk[4] = (short)f2bf(rbf[i][1].x); pk[5] = (short)f2bf(rbf[i][1].y);
      pk[6] = (short)f2bf(rbf[i][1].z); pk[7] = (short)f2bf(rbf[i][1].w);
      *(short8*)&Bs[buf][rloc * 32 + (sl ^ ((rsub >> 1) & 3)) * 8] = pk;
    }
  };

  int NT = K >> 5;   // K-steps of 32 (all K are multiples of 32)
  int ksw = (c >> 1) & 3;   // read-side kslot swizzle for this lane's rows

  if constexpr (MODE == 4) {
    // ---- 2-buffer drain schedule (lin head, small share of runtime) ----
    STAGE(0, 0);
    LOADW(0);
    WRITEW(0);
    asm volatile("s_waitcnt vmcnt(0) lgkmcnt(0)" ::: "memory");
    __builtin_amdgcn_s_barrier();
    int cur = 0;
    for (int t = 0; t < NT; ++t) {
      short8 afr[4], bfr[4];
#pragma unroll
      for (int mt2 = 0; mt2 < 4; mt2++)
        afr[mt2] = *(const short8*)&As[cur][(wr * 64 + mt2 * 16 + c) * 32 + (q ^ ksw) * 8];
#pragma unroll
      for (int nt2 = 0; nt2 < 4; nt2++)
        bfr[nt2] = *(const short8*)&Bs[cur][(wc * 64 + nt2 * 16 + c) * 32 + (q ^ ksw) * 8];
      asm volatile("s_waitcnt lgkmcnt(0)" ::: "memory");
      __builtin_amdgcn_sched_barrier(0);
      __builtin_amdgcn_s_barrier();
      if (t + 1 < NT) { STAGE(t + 1, cur ^ 1); LOADW(t + 1); WRITEW(cur ^ 1); }
      __builtin_amdgcn_sched_barrier(0);
#pragma unroll
      for (int mt2 = 0; mt2 < 4; mt2++)
#pragma unroll
        for (int nt2 = 0; nt2 < 4; nt2++)
          acc[mt2][nt2] = __builtin_amdgcn_mfma_f32_16x16x32_bf16(
              afr[mt2], bfr[nt2], acc[mt2][nt2], 0, 0, 0);
      if (t + 1 < NT) {
        asm volatile("s_waitcnt vmcnt(0) lgkmcnt(0)" ::: "memory");
        __builtin_amdgcn_s_barrier();
        cur ^= 1;
      }
    }
  } else {
    // ---- triple-buffer, 1 barrier per K-step ----
    STAGE(0, 0);
    if (NT > 1) {
      STAGE(1, 1);
      asm volatile("s_waitcnt vmcnt(4)" ::: "memory");   // tile 0 complete
    } else {
      asm volatile("s_waitcnt vmcnt(0)" ::: "memory");
    }
    __builtin_amdgcn_s_barrier();

    int cb = 0, sb = 2;   // current buf = t%3, stage buf = (t+2)%3
    for (int t = 0; t < NT; ++t) {
      short8 afr[4], bfr[4];
#pragma unroll
      for (int mt2 = 0; mt2 < 4; mt2++)
        afr[mt2] = *(const short8*)&As[cb][(wr * 64 + mt2 * 16 + c) * 32 + (q ^ ksw) * 8];
#pragma unroll
      for (int nt2 = 0; nt2 < 4; nt2++)
        bfr[nt2] = *(const short8*)&Bs[cb][(wc * 64 + nt2 * 16 + c) * 32 + (q ^ ksw) * 8];
      if (t + 2 < NT) STAGE(t + 2, sb);    // different buffer than any reader
      __builtin_amdgcn_sched_barrier(0);
#pragma unroll
      for (int mt2 = 0; mt2 < 4; mt2++)
#pragma unroll
        for (int nt2 = 0; nt2 < 4; nt2++)
          acc[mt2][nt2] = __builtin_amdgcn_mfma_f32_16x16x32_bf16(
              afr[mt2], bfr[nt2], acc[mt2][nt2], 0, 0, 0);
      if (t + 1 < NT) {
        if (t + 2 < NT)
          asm volatile("s_waitcnt vmcnt(4)" ::: "memory");  // t+1 done; t+2 in flight
        else
          asm volatile("s_waitcnt vmcnt(0)" ::: "memory");
        __builtin_amdgcn_s_barrier();                       // the ONLY barrier
      }
      cb = (cb == 2) ? 0 : cb + 1;
      sb = (sb == 2) ? 0 : sb + 1;
    }
  }

  // ---- epilogue ----
#pragma unroll
  for (int mt2 = 0; mt2 < 4; mt2++) {
    int row0 = mBase + wr * 64 + mt2 * 16 + q * 4;
#pragma unroll
    for (int nt2 = 0; nt2 < 4; nt2++) {
      int col = nBase + wc * 64 + nt2 * 16 + c;
      float bv = (MODE == 0 || MODE == 1 || MODE == 3) ? bias[col] : 0.f;
      f32x4 v = acc[mt2][nt2];
#pragma unroll
      for (int e = 0; e < 4; e++) {
        int row = row0 + e;
        float x = v[e] + bv;
        if (MODE == 0) x = fminf(fmaxf(x, 0.f), 6.f);
        if (MODE == 3) x += res[(size_t)row * N + col];
        if (MODE == 0 || MODE == 2) outU[(size_t)row * N + col] = f2bf(x);
        else                        outF[(size_t)row * N + col] = x;
      }
    }
  }
}

// ---------------------------------------------------------------------------
// Bucket LUT: lut[i][j] (u8, stride 224) = rp bucket 0..48 for j<196, 49
// (sentinel -> Rw[..][49] = -inf) for j in [196,224). Same for all (b,h).
// ---------------------------------------------------------------------------
__global__ __launch_bounds__(224) void blut_k(uint8_t* __restrict__ lut)
{
  int i = blockIdx.x;          // 0..195
  int j = threadIdx.x;         // 0..223
  uint8_t v = 49;
  if (j < 196) {
    int ri = i / 14, ci = i - ri * 14;
    int rj = j / 14, cj = j - rj * 14;
    int dr = ri - rj, dc = ci - cj;
    int adr = dr < 0 ? -dr : dr, adc = dc < 0 ? -dc : dc;
    int tr = adr <= 1 ? adr : (adr <= 3 ? 2 : 3);
    int tc = adc <= 1 ? adc : (adc <= 3 ? 2 : 3);
    int fr = dr < 0 ? -tr : tr, fc = dc < 0 ? -tc : tc;
    v = (uint8_t)(fr * 7 + fc + 24);
  }
  lut[i * 224 + j] = v;
}

// ---------------------------------------------------------------------------
// Fused attention per (b,h), flash-style over 7 j-chunks of 32, 2-tile ILP.
// (unchanged from r19/r20: exp2 domain via raw __builtin_amdgcn_exp2f)
// ---------------------------------------------------------------------------
__global__ __launch_bounds__(256) void attn_k(
    const u16* __restrict__ QKV, const float* __restrict__ tabG,
    const uint8_t* __restrict__ lutG, u16* __restrict__ AO)
{
  __shared__ __align__(16) u16 Ks[4 * 196 * 8];      // [s][j][e] K fragments
  __shared__ __align__(16) u16 Vt[32 * 228];         // [d][j], pad j>=196 zero
  __shared__ __align__(16) u16 Pc4[4][2][512];       // per-wave, per-tile P chunk
  __shared__ __align__(16) u16 Ts[49 * 32];          // rpe table, [t][k] bf16
  __shared__ __align__(16) u16 Rw4[4][2][16 * 50];   // per-wave, per-tile rpe
  int bh = blockIdx.x; int b = bh / NH_, h = bh % NH_;
  int tid = threadIdx.x;
  int wv = tid >> 6, ln = tid & 63;
  int q = ln >> 4, c = ln & 15;
  size_t rowbase = (size_t)b * NPOS * 1152 + h * 32;

  // ---- stage K fragments via global_load_lds (wave-uniform dest) ----
  for (int cb = wv * 64; cb < 784; cb += 256) {
    int ch = cb + ln;
    if (ch < 784) {
      int s = ch / 196, j = ch - s * 196;
      GLDS16(QKV + rowbase + 384 + (size_t)j * 1152 + s * 8, &Ks[cb * 8]);
    }
  }
  // ---- stage rpe table transposed to [t][k] bf16 (once per block) ----
  for (int t = tid; t < 49 * 32; t += 256) {
    int tt = t >> 5, k = t & 31;
    Ts[t] = f2bf(tabG[k * 49 + tt]);
  }
  // ---- stage V transposed (vectorized) ----
  for (int t = tid; t < 784; t += 256) {
    int nn = t >> 2, d0 = (t & 3) * 8;
    short8 v = *(const short8*)(QKV + rowbase + 768 + (size_t)nn * 1152 + d0);
#pragma unroll
    for (int j = 0; j < 8; j++) Vt[(d0 + j) * 228 + nn] = (u16)v[j];
  }
  for (int t = tid; t < 32 * 32; t += 256) {
    int d = t >> 5, jj = 196 + (t & 31);
    Vt[d * 228 + jj] = 0;
  }
  __syncthreads();

  for (int it = 0; it < 2; ++it) {
    int mtA = wv + it * 8;                 // always < 13 (wv<=3 -> <=11)
    bool vB = (mtA + 4) < 13;
    int mbx[2];
    mbx[0] = mtA * 16;
    mbx[1] = (vB ? (mtA + 4) : 12) * 16;   // clamp; discarded if !vB

    short8 afrag[2];
    int i0x[2], lutOff[2][4];
#pragma unroll
    for (int x = 0; x < 2; x++) {
      int irow = mbx[x] + c; if (irow > 195) irow = 195;
      afrag[x] = *(const short8*)(QKV + rowbase + (size_t)irow * 1152 + q * 8);
      i0x[x] = mbx[x] + q * 4;
#pragma unroll
      for (int e = 0; e < 4; e++) {
        int i = i0x[x] + e; if (i > 195) i = 195;
        lutOff[x][e] = i * 224;
      }
    }
    int rwOff[4];
#pragma unroll
    for (int e = 0; e < 4; e++) rwOff[e] = (q * 4 + e) * 50;

    // ---- rpe scores via MFMA -> Rw, exp2 domain (SCALE2) ----
#pragma unroll
    for (int nt = 0; nt < 4; nt++) {
      int t = nt * 16 + c;
      int tt = t < 49 ? t : 48;
      short8 tb = *(const short8*)&Ts[tt * 32 + q * 8];
#pragma unroll
      for (int x = 0; x < 2; x++) {
        f32x4 z = {0.f, 0.f, 0.f, 0.f};
        f32x4 rr = __builtin_amdgcn_mfma_f32_16x16x32_bf16(afrag[x], tb, z, 0, 0, 0);
        if (t < 49) {
#pragma unroll
          for (int e = 0; e < 4; e++)
            Rw4[wv][x][rwOff[e] + t] = f2bf(rr[e] * SCALE2);
        }
      }
    }
    if (c == 0) {
#pragma unroll
      for (int x = 0; x < 2; x++)
#pragma unroll
        for (int e = 0; e < 4; e++)
          Rw4[wv][x][rwOff[e] + 49] = 0xFF80;   // bf16 -inf
    }

    float mr[2] = {-INFINITY, -INFINITY};
    float l4[2][4] = {{0.f,0.f,0.f,0.f},{0.f,0.f,0.f,0.f}};
    f32x4 oacc[2][2];
#pragma unroll
    for (int x = 0; x < 2; x++) {
      oacc[x][0] = (f32x4){0.f, 0.f, 0.f, 0.f};
      oacc[x][1] = (f32x4){0.f, 0.f, 0.f, 0.f};
    }

    // ---- online softmax over 7 chunks of 32 j, two tiles interleaved ----
    for (int ck = 0; ck < 7; ck++) {
      // shared K fragments for both tiles
      short8 bfr[2];
#pragma unroll
      for (int t = 0; t < 2; t++) {
        int j = (ck * 2 + t) * 16 + c;
        int jc = j > 195 ? 195 : j;
        bfr[t] = *(const short8*)&Ks[(q * 196 + jc) * 8];
      }
      f32x4 s01[2][2];
#pragma unroll
      for (int x = 0; x < 2; x++) {
        f32x4 z = {0.f, 0.f, 0.f, 0.f};
        s01[x][0] = __builtin_amdgcn_mfma_f32_16x16x32_bf16(afrag[x], bfr[0], z, 0, 0, 0);
        s01[x][1] = __builtin_amdgcn_mfma_f32_16x16x32_bf16(afrag[x], bfr[1], z, 0, 0, 0);
      }
      // bucket LUT loads -> Rw gather (mask folded in via sentinel)
      uint8_t bk[2][2][4];
#pragma unroll
      for (int t = 0; t < 2; t++) {
        int jj = ck * 32 + t * 16 + c;
#pragma unroll
        for (int x = 0; x < 2; x++)
#pragma unroll
          for (int e = 0; e < 4; e++) bk[x][t][e] = lutG[lutOff[x][e] + jj];
      }
#pragma unroll
      for (int x = 0; x < 2; x++)
#pragma unroll
        for (int t = 0; t < 2; t++)
#pragma unroll
          for (int e = 0; e < 4; e++)
            s01[x][t][e] = s01[x][t][e] * SCALE2 + bf2f(Rw4[wv][x][rwOff[e] + bk[x][t][e]]);

      // per-tile shared chunk max + rescale + raw exp2 + P store (branch-free)
#pragma unroll
      for (int x = 0; x < 2; x++) {
        float mc = s01[x][0][0];
#pragma unroll
        for (int t = 0; t < 2; t++)
#pragma unroll
          for (int e = 0; e < 4; e++) mc = fmaxf(mc, s01[x][t][e]);
#pragma unroll
        for (int o = 1; o < 16; o <<= 1) mc = fmaxf(mc, __shfl_xor(mc, o, 64));
        float mn = fmaxf(mr[x], mc);
        float sc = __builtin_amdgcn_exp2f(mr[x] - mn);
        mr[x] = mn;
#pragma unroll
        for (int t = 0; t < 2; t++)
#pragma unroll
          for (int e = 0; e < 4; e++) s01[x][t][e] = __builtin_amdgcn_exp2f(s01[x][t][e] - mn);
#pragma unroll
        for (int e = 0; e < 4; e++) {
          l4[x][e] = l4[x][e] * sc + s01[x][0][e] + s01[x][1][e];
          oacc[x][0][e] *= sc; oacc[x][1][e] *= sc;
        }
#pragma unroll
        for (int t = 0; t < 2; t++) {
          int sl2 = t * 2 + (c >> 3);
#pragma unroll
          for (int e = 0; e < 4; e++) {
            union { float f; uint32_t u; } pv; pv.f = s01[x][t][e];
            Pc4[wv][x][(sl2 * 16 + q * 4 + e) * 8 + (c & 7)] = (u16)(pv.u >> 16);
          }
        }
      }
      // PV: shared V fragment, 2 MFMAs per tile
#pragma unroll
      for (int n2 = 0; n2 < 2; n2++) {
        short8 vb = *(const short8*)&Vt[(n2 * 16 + c) * 228 + ck * 32 + q * 8];
#pragma unroll
        for (int x = 0; x < 2; x++) {
          short8 pa = *(const short8*)&Pc4[wv][x][(q * 16 + c) * 8];
          oacc[x][n2] = __builtin_amdgcn_mfma_f32_16x16x32_bf16(pa, vb, oacc[x][n2], 0, 0, 0);
        }
      }
    }

    // ---- final 1/l and store per tile ----
#pragma unroll
    for (int x = 0; x < 2; x++) {
      if (x == 1 && !vB) continue;
      float inv[4];
#pragma unroll
      for (int e = 0; e < 4; e++) {
        float s2 = l4[x][e];
#pragma unroll
        for (int o = 1; o < 16; o <<= 1) s2 += __shfl_xor(s2, o, 64);
        inv[e] = 1.f / s2;
      }
#pragma unroll
      for (int n2 = 0; n2 < 2; n2++) {
#pragma unroll
        for (int e = 0; e < 4; e++) {
          int i = i0x[x] + e;
          if (i < 196) {
            int d = n2 * 16 + c;
            AO[((size_t)b * NPOS + i) * DM + h * 32 + d] = f2bf(oacc[x][n2][e] * inv[e]);
          }
        }
      }
    }
  }
}

// ---------------------------------------------------------------------------
// x (B, CIN, HW, HW) f32  ->  A_t (B*NPOS, CIN) bf16
// ---------------------------------------------------------------------------
__global__ __launch_bounds__(256) void transpose_cast_k(
    const float* __restrict__ x, u16* __restrict__ At)
{
  __shared__ float t[32][33];
  int c0 = blockIdx.x * 32, n0 = blockIdx.y * 32, b = blockIdx.z;
  int tx = threadIdx.x, ty = threadIdx.y;
  const float* xb = x + (size_t)b * CIN * NPOS;
#pragma unroll
  for (int i = 0; i < 4; i++) {
    int cc = c0 + ty + i * 8, nn = n0 + tx;
    t[ty + i * 8][tx] = (nn < NPOS) ? xb[(size_t)cc * NPOS + nn] : 0.f;
  }
  __syncthreads();
  u16* Ab = At + (size_t)b * NPOS * CIN;
#pragma unroll
  for (int i = 0; i < 4; i++) {
    int nn = n0 + ty + i * 8, cc = c0 + tx;
    if (nn < NPOS) Ab[(size_t)nn * CIN + cc] = f2bf(t[tx][ty + i * 8]);
  }
}

// ---------------------------------------------------------------------------
// r21: FUSED depthwise 3x3 conv + bias + residual + LayerNorm.
//   One wave per row (b,n): conv accumulate 6 ch/lane (ch = lane + 64j,
//   coalesced), write T1 (f32, needed as proj residual), wave-shfl LN stats,
//   write H (bf16).  Eliminates the 38.5MB T1 re-read of the old ln_k pass
//   and one kernel launch.  pcw (13.8KB) is L1-resident.
// ---------------------------------------------------------------------------
__global__ __launch_bounds__(256) void convln_k(
    const float* __restrict__ T0, const float* __restrict__ pcw,
    const float* __restrict__ pcb, const float* __restrict__ lnw,
    const float* __restrict__ lnb, float* __restrict__ T1,
    u16* __restrict__ H)
{
  int row = blockIdx.x * 4 + (threadIdx.x >> 6);   // global row = b*196+n
  int ln = threadIdx.x & 63;
  int b = row / NPOS, n = row - b * NPOS;
  int hh = n / 14, ww = n % 14;
  const float* base = T0 + (size_t)b * NPOS * DM;

  float acc6[6];
#pragma unroll
  for (int j = 0; j < 6; j++) {
    int ch = ln + 64 * j;
    acc6[j] = base[(size_t)n * DM + ch] + pcb[ch];   // identity residual + bias
  }
#pragma unroll
  for (int kh = 0; kh < 3; kh++) {
    int h2 = hh + kh - 1;
    if (h2 < 0 || h2 >= 14) continue;
#pragma unroll
    for (int kw = 0; kw < 3; kw++) {
      int w2 = ww + kw - 1;
      if (w2 < 0 || w2 >= 14) continue;
      const float* nb = base + (size_t)(h2 * 14 + w2) * DM;
      int t = kh * 3 + kw;
#pragma unroll
      for (int j = 0; j < 6; j++) {
        int ch = ln + 64 * j;
        acc6[j] += nb[ch] * pcw[ch * 9 + t];
      }
    }
  }
  // write T1 + LN stats in one pass
  float* t1row = T1 + (size_t)row * DM;
  float s = 0.f, sq = 0.f;
#pragma unroll
  for (int j = 0; j < 6; j++) {
    t1row[ln + 64 * j] = acc6[j];
    s += acc6[j]; sq += acc6[j] * acc6[j];
  }
#pragma unroll
  for (int o = 1; o < 64; o <<= 1) { s += __shfl_xor(s, o, 64); sq += __shfl_xor(sq, o, 64); }
  float mu = s * (1.f / 384.f);
  float var = sq * (1.f / 384.f) - mu * mu;
  float rs = rsqrtf(var + 1e-5f);
  u16* hrow = H + (size_t)row * DM;
#pragma unroll
  for (int j = 0; j < 6; j++) {
    int d = ln + 64 * j;
    hrow[d] = f2bf((acc6[j] - mu) * rs * lnw[d] + lnb[d]);
  }
}

// ---------------------------------------------------------------------------
// LayerNorm(384) f32 -> bf16, one wave per row (float2-vectorized) — LN2
// ---------------------------------------------------------------------------
__global__ __launch_bounds__(256) void ln_k(
    const float* __restrict__ in, const float* __restrict__ w,
    const float* __restrict__ bb, u16* __restrict__ out)
{
  int row = blockIdx.x * 4 + (threadIdx.x >> 6);
  int ln = threadIdx.x & 63;
  const float2* r = (const float2*)(in + (size_t)row * DM);
  float2 v[3]; float s = 0.f, sq = 0.f;
#pragma unroll
  for (int j = 0; j < 3; j++) {
    v[j] = r[ln + 64 * j];
    s += v[j].x + v[j].y; sq += v[j].x * v[j].x + v[j].y * v[j].y;
  }
#pragma unroll
  for (int o = 1; o < 64; o <<= 1) { s += __shfl_xor(s, o, 64); sq += __shfl_xor(sq, o, 64); }
  float mu = s * (1.f / 384.f);
  float var = sq * (1.f / 384.f) - mu * mu;
  float rs = rsqrtf(var + 1e-5f);
  uint32_t* orow = (uint32_t*)(out + (size_t)row * DM);
#pragma unroll
  for (int j = 0; j < 3; j++) {
    int d = (ln + 64 * j) * 2;
    float a = (v[j].x - mu) * rs * w[d] + bb[d];
    float bq = (v[j].y - mu) * rs * w[d + 1] + bb[d + 1];
    orow[ln + 64 * j] = (uint32_t)f2bf(a) | ((uint32_t)f2bf(bq) << 16);
  }
}

// ---------------------------------------------------------------------------
// BN1 over (batch, dmodel) per position n: two-stage stats
// ---------------------------------------------------------------------------
__global__ __launch_bounds__(256) void bn1_partial_k(
    const float* __restrict__ T3, float* __restrict__ part)
{
  int n = blockIdx.x >> 3, g = blockIdx.x & 7;
  int tid = threadIdx.x;
  float s = 0.f, sq = 0.f;
  for (int b2 = g * 16; b2 < g * 16 + 16; b2++) {
    const float* p = T3 + ((size_t)b2 * NPOS + n) * DM;
    for (int d = tid; d < DM; d += 256) { float v = p[d]; s += v; sq += v * v; }
  }
#pragma unroll
  for (int o = 1; o < 64; o <<= 1) { s += __shfl_xor(s, o, 64); sq += __shfl_xor(sq, o, 64); }
  __shared__ float ls[4], lq[4];
  int wv = tid >> 6, ln = tid & 63;
  if (ln == 0) { ls[wv] = s; lq[wv] = sq; }
  __syncthreads();
  if (tid == 0) {
    part[blockIdx.x * 2]     = ls[0] + ls[1] + ls[2] + ls[3];
    part[blockIdx.x * 2 + 1] = lq[0] + lq[1] + lq[2] + lq[3];
  }
}

__global__ __launch_bounds__(256) void bn1_finish_k(
    const float* __restrict__ part, const float* __restrict__ bw,
    const float* __restrict__ bbb, float* __restrict__ scaleArr,
    float* __restrict__ shiftArr)
{
  int n = threadIdx.x;
  if (n >= NPOS) return;
  float S = 0.f, Q = 0.f;
#pragma unroll
  for (int g = 0; g < 8; g++) { S += part[(n * 8 + g) * 2]; Q += part[(n * 8 + g) * 2 + 1]; }
  float mu = S / 49152.f;
  float var = Q / 49152.f - mu * mu;
  float rs = rsqrtf(var + 2e-5f);
  float sc = rs * bw[n];
  scaleArr[n] = sc;
  shiftArr[n] = bbb[n] - mu * sc;
}

__global__ __launch_bounds__(256) void bn1_apply_k(
    const float* __restrict__ T3, const float* __restrict__ scaleArr,
    const float* __restrict__ shiftArr, u16* __restrict__ outb)
{
  int idx = blockIdx.x * 256 + threadIdx.x;           // float4 index
  if (idx >= MT * DM / 4) return;
  int n = (idx / 96) % NPOS;
  float4 v = *(const float4*)(T3 + (size_t)idx * 4);
  float sc = scaleArr[n], sh = shiftArr[n];
  uint32_t p0 = (uint32_t)f2bf(v.x * sc + sh) | ((uint32_t)f2bf(v.y * sc + sh) << 16);
  uint32_t p1 = (uint32_t)f2bf(v.z * sc + sh) | ((uint32_t)f2bf(v.w * sc + sh) << 16);
  ((uint2*)outb)[idx] = make_uint2(p0, p1);
}

// ---------------------------------------------------------------------------
// split-K reduce for lin head + bias
// ---------------------------------------------------------------------------
__global__ __launch_bounds__(256) void lin_reduce_k(
    const float* __restrict__ part, const float* __restrict__ lb,
    float* __restrict__ y)
{
  int idx = blockIdx.x * 256 + threadIdx.x;
  if (idx >= 128 * DM) return;
  int col = idx % DM;
  float s = lb[col];
#pragma unroll
  for (int sp = 0; sp < 49; sp++) s += part[(size_t)sp * (128 * DM) + idx];
  y[idx] = s;
}

// ---------------------------------------------------------------------------
// BN2 over batch (128) per feature col, in-place on y
// ---------------------------------------------------------------------------
__global__ __launch_bounds__(64) void bn2_k(
    float* __restrict__ y, const float* __restrict__ w,
    const float* __restrict__ bb)
{
  int col = blockIdx.x; int ln = threadIdx.x;
  float v0 = y[(size_t)ln * DM + col];
  float v1 = y[(size_t)(ln + 64) * DM + col];
  float s = v0 + v1, sq = v0 * v0 + v1 * v1;
#pragma unroll
  for (int o = 1; o < 64; o <<= 1) { s += __shfl_xor(s, o, 64); sq += __shfl_xor(sq, o, 64); }
  float mu = s / 128.f;
  float var = sq / 128.f - mu * mu;
  float rs = rsqrtf(var + 2e-5f);
  float sc = rs * w[col], sh = bb[col] - mu * sc;
  y[(size_t)ln * DM + col] = v0 * sc + sh;
  y[(size_t)(ln + 64) * DM + col] = v1 * sc + sh;
}

// ---------------------------------------------------------------------------
// merged f32 -> bf16 cast for the six small weight matrices
// ---------------------------------------------------------------------------
__global__ __launch_bounds__(256) void castall_k(
    const float* __restrict__ s0, u16* __restrict__ d0,
    const float* __restrict__ s1, u16* __restrict__ d1,
    const float* __restrict__ s2, u16* __restrict__ d2,
    const float* __restrict__ s3, u16* __restrict__ d3,
    const float* __restrict__ s4, u16* __restrict__ d4,
    const float* __restrict__ s5, u16* __restrict__ d5)
{
  const int b0 = 262144, b1 = b0 + 98304, b2 = b1 + 110592,
            b3 = b2 + 36864, b4 = b3 + 147456, b5 = b4 + 147456; // 802816
  int idx = blockIdx.x * 256 + threadIdx.x;
  int stride = gridDim.x * 256;
  for (; idx < b5; idx += stride) {
    const float* s; u16* d; int l;
    if      (idx < b0) { s = s0; d = d0; l = idx; }
    else if (idx < b1) { s = s1; d = d1; l = idx - b0; }
    else if (idx < b2) { s = s2; d = d2; l = idx - b1; }
    else if (idx < b3) { s = s3; d = d3; l = idx - b2; }
    else if (idx < b4) { s = s4; d = d4; l = idx - b3; }
    else               { s = s5; d = d5; l = idx - b4; }
    float4 v = *(const float4*)(s + (size_t)l * 4);
    uint32_t p0 = (uint32_t)f2bf(v.x) | ((uint32_t)f2bf(v.y) << 16);
    uint32_t p1 = (uint32_t)f2bf(v.z) | ((uint32_t)f2bf(v.w) << 16);
    ((uint2*)d)[l] = make_uint2(p0, p1);
  }
}

// ---------------------------------------------------------------------------
// Orchestration
// ---------------------------------------------------------------------------
extern "C" void kernel_launch(void* const* d_in, const int* in_sizes, int n_in,
                              void* d_out, int out_size, void* d_ws, size_t ws_size,
                              hipStream_t stream)
{
  (void)in_sizes; (void)n_in; (void)out_size;
  const float* x    = (const float*)d_in[0];
  const float* fc1w = (const float*)d_in[1];
  const float* fc1b = (const float*)d_in[2];
  const float* fc2w = (const float*)d_in[3];
  const float* fc2b = (const float*)d_in[4];
  const float* pcw  = (const float*)d_in[5];
  const float* pcb  = (const float*)d_in[6];
  const float* ln1w = (const float*)d_in[7];
  const float* ln1b = (const float*)d_in[8];
  const float* qkvw = (const float*)d_in[9];
  const float* rpet = (const float*)d_in[10];
  const float* projw= (const float*)d_in[11];
  const float* projb= (const float*)d_in[12];
  const float* ln2w = (const float*)d_in[13];
  const float* ln2b = (const float*)d_in[14];
  const float* m1w  = (const float*)d_in[15];
  const float* m1b  = (const float*)d_in[16];
  const float* m2w  = (const float*)d_in[17];
  const float* m2b  = (const float*)d_in[18];
  const float* bn1w = (const float*)d_in[19];
  const float* bn1b = (const float*)d_in[20];
  const float* linw = (const float*)d_in[21];
  const float* linb = (const float*)d_in[22];
  const float* bn2w = (const float*)d_in[23];
  const float* bn2b = (const float*)d_in[24];
  float* y = (float*)d_out;

  // -------- aliased workspace layout (regions share by liveness) ----------
  const size_t RA = 0;                      // At / MLP1
  const size_t RB = 77070336;               // U / QKV / T3nb
  const size_t RC = RB + 57802752;          // H / AO / H2
  const size_t RD = RC + 19267584;          // T0 / T2
  const size_t RE = RD + 38535168;          // T1 / T3
  const size_t RF = RE + 38535168;          // PART (lin split-K)
  const size_t RG = RF + 9633792;           // small bf16 weights
  const size_t RS = RG + 6422528;           // bn1 scale/shift + partials + lut
  const size_t NEED = RS + 2048 + 16384 + 45056;
  if (ws_size < NEED) return;

  char* ws = (char*)d_ws;
  u16*   At    = (u16*)(ws + RA);
  u16*   MLP1  = (u16*)(ws + RA);
  u16*   U     = (u16*)(ws + RB);
  u16*   QKV   = (u16*)(ws + RB);
  u16*   T3nb  = (u16*)(ws + RB);
  u16*   H     = (u16*)(ws + RC);
  u16*   AO    = (u16*)(ws + RC);
  u16*   H2    = (u16*)(ws + RC);
  float* T0    = (float*)(ws + RD);
  float* T2    = (float*)(ws + RD);
  float* T1    = (float*)(ws + RE);
  float* T3    = (float*)(ws + RE);
  float* PART  = (float*)(ws + RF);
  u16*   wb_fc1 = (u16*)(ws + RG);
  u16*   wb_fc2 = wb_fc1 + 1048576;
  u16*   wb_qkv = wb_fc2 + 393216;
  u16*   wb_proj= wb_qkv + 442368;
  u16*   wb_m1  = wb_proj + 147456;
  u16*   wb_m2  = wb_m1 + 589824;
  float* bnS   = (float*)(ws + RS);
  float* bnSh  = bnS + 196;
  float* bnP   = (float*)(ws + RS + 2048);
  uint8_t* blut = (uint8_t*)(ws + RS + 2048 + 16384);

  // weight casts (f32 -> bf16), one merged kernel + bucket LUT
  castall_k<<<1024, 256, 0, stream>>>(fc1w, wb_fc1, fc2w, wb_fc2, qkvw, wb_qkv,
                                      projw, wb_proj, m1w, wb_m1, m2w, wb_m2);
  blut_k<<<196, 224, 0, stream>>>(blut);

  // x (B,CIN,N) -> At (B*N, CIN) bf16
  transpose_cast_k<<<dim3(32, 7, 128), dim3(32, 8), 0, stream>>>(x, At);

  // embed fc1: U = relu6(At @ fc1w^T + b)   [25088 x 1024]
  gemm_k<0><<<196 * 8, 256, 0, stream>>>(At, wb_fc1, fc1b, nullptr, U,
                                          MT, 1024, 1024, 1024, 1024, 8, 0);
  // embed fc2: T0 = U @ fc2w^T + b          [25088 x 384] f32
  gemm_k<1><<<196 * 3, 256, 0, stream>>>(U, wb_fc2, fc2b, nullptr, T0,
                                          MT, 384, 1024, 1024, 1024, 3, 0);
  // FUSED depthwise conv + bias + residual + LN1 -> T1 (f32), H (bf16)
  convln_k<<<MT / 4, 256, 0, stream>>>(T0, pcw, pcb, ln1w, ln1b, T1, H);
  // qkv: QKV = H @ qkvw^T (no bias)          [25088 x 1152] bf16
  gemm_k<2><<<196 * 9, 256, 0, stream>>>(H, wb_qkv, nullptr, nullptr, QKV,
                                          MT, 1152, 384, 384, 384, 9, 0);
  // fused attention (rpe in-kernel, flash-style, LUT bias, 2-tile ILP) -> AO
  attn_k<<<1536, 256, 0, stream>>>(QKV, rpet, blut, AO);
  // proj + residual(T1) -> T2 (f32)
  gemm_k<3><<<196 * 3, 256, 0, stream>>>(AO, wb_proj, projb, T1, T2,
                                          MT, 384, 384, 384, 384, 3, 0);
  // LN2 -> H2 (bf16)
  ln_k<<<MT / 4, 256, 0, stream>>>(T2, ln2w, ln2b, H2);
  // mlp fc1: MLP1 = relu6(H2 @ m1w^T + b)    [25088 x 1536] bf16
  gemm_k<0><<<196 * 12, 256, 0, stream>>>(H2, wb_m1, m1b, nullptr, MLP1,
                                           MT, 1536, 384, 384, 384, 12, 0);
  // mlp fc2 + residual(T2) -> T3 (f32)
  gemm_k<3><<<196 * 3, 256, 0, stream>>>(MLP1, wb_m2, m2b, T2, T3,
                                          MT, 384, 1536, 1536, 1536, 3, 0);
  // BN1 (per position) -> T3nb (bf16)
  bn1_partial_k<<<196 * 8, 256, 0, stream>>>(T3, bnP);
  bn1_finish_k<<<1, 256, 0, stream>>>(bnP, bn1w, bn1b, bnS, bnSh);
  bn1_apply_k<<<(MT * DM / 4 + 255) / 256, 256, 0, stream>>>(T3, bnS, bnSh, T3nb);
  // lin head: y = T3nb(128 x 75264) @ linw^T, split-K 49 x 1536 (W f32 direct)
  gemm_k<4><<<3 * 49, 256, 0, stream>>>(T3nb, linw, nullptr, nullptr, PART,
                                         128, 384, 1536, 75264, 75264, 3, 1536);
  lin_reduce_k<<<192, 256, 0, stream>>>(PART, linb, y);
  // BN2 (per feature over batch), in place on d_out
  bn2_k<<<384, 64, 0, stream>>>(y, bn2w, bn2b);
}

// Round 22
// 547.190 us; speedup vs baseline: 1.0468x; 1.0468x over previous
//
#include <hip/hip_runtime.h>
#include <cstdint>

// ---------------------------------------------------------------------------
// Problem constants
// ---------------------------------------------------------------------------
#define B_    128
#define CIN   1024
#define NPOS  196          // 14*14
#define DM    384
#define NH_   12
#define HD_   32
#define DFF_  1536
#define MT    25088        // B_*NPOS
#define SCALE_Q 0.17677669529663687f   // 1/sqrt(32)
#define SCALE2  0.25503485810335155f   // SCALE_Q * log2(e)  (exp2 domain)

typedef unsigned short u16;
typedef __attribute__((ext_vector_type(8))) short  short8;   // 8 bf16 (4 VGPR)
typedef __attribute__((ext_vector_type(4))) float  f32x4;    // MFMA C/D

__device__ __forceinline__ u16 f2bf(float f) {
  union { float f; uint32_t u; } v; v.f = f;
  uint32_t u = v.u;
  return (u16)((u + 0x7fffu + ((u >> 16) & 1u)) >> 16);
}
__device__ __forceinline__ float bf2f(u16 h) {
  union { uint32_t u; float f; } v; v.u = ((uint32_t)h) << 16;
  return v.f;
}

#define GLDS16(g, l)                                                           \
  __builtin_amdgcn_global_load_lds(                                            \
      (const __attribute__((address_space(1))) void*)(g),                      \
      (__attribute__((address_space(3))) void*)(l), 16, 0, 0)

// ---------------------------------------------------------------------------
// Generic bf16 MFMA GEMM (r20 best: triple-buffer, 1 barrier/K-step; GLDS
// with pre-swizzled source; counted vmcnt; XCD-chunked bijective swizzle).
// MODE: 0 = bias+relu6 -> bf16 | 1 = bias -> f32 | 2 = plain -> bf16
//       3 = bias+res -> f32    | 4 = split-K partial -> f32
// ---------------------------------------------------------------------------
template <int MODE>
__global__ __launch_bounds__(256) void gemm_k(
    const u16* __restrict__ A, const void* __restrict__ Wv,
    const float* __restrict__ bias, const float* __restrict__ res,
    void* __restrict__ outp,
    int M, int N, int K, int lda, int ldw, int nTN, int splitK)
{
  __shared__ __align__(16) u16 As[3][128 * 32];   // row-major [r][kphys]
  __shared__ __align__(16) u16 Bs[3][128 * 32];

  int nwg = gridDim.x;
  int bid0 = blockIdx.x;
  int qq = nwg >> 3, rr = nwg & 7;
  int xcd = bid0 & 7, idx = bid0 >> 3;
  int bid = (xcd < rr ? xcd * (qq + 1) : rr * (qq + 1) + (xcd - rr) * qq) + idx;

  int split = 0, mT, nT;
  if (MODE == 4) { split = bid / nTN; nT = bid % nTN; mT = 0; }
  else           { mT = bid / nTN;    nT = bid % nTN; }

  const u16* Ab = A + (size_t)split * splitK;
  float* outF = (float*)outp + ((MODE == 4) ? (size_t)split * (size_t)M * N : (size_t)0);
  u16*   outU = (u16*)outp;

  int tid = threadIdx.x;
  int wv = tid >> 6, ln = tid & 63;
  int q = ln >> 4, c = ln & 15;
  int wr = wv >> 1, wc = wv & 1;
  int mBase = mT * 128, nBase = nT * 128;

  f32x4 acc[4][4];
#pragma unroll
  for (int i = 0; i < 4; i++)
#pragma unroll
    for (int j = 0; j < 4; j++) acc[i][j] = (f32x4){0.f, 0.f, 0.f, 0.f};

  const u16* Ag = Ab + (size_t)mBase * lda;
  const u16*  Wg16 = (const u16*)Wv + (size_t)split * splitK + (size_t)nBase * ldw;
  const float* Wg32 = (const float*)Wv + (size_t)split * splitK + (size_t)nBase * ldw;

  int sl = ln & 3, rsub = ln >> 2;          // lane -> (phys kslot, row-in-16)
  int lk = sl ^ ((rsub >> 1) & 3);          // logical kslot this lane fetches

  float4 rbf[2][2];                         // MODE 4: raw f32 W held in regs

  auto STAGE = [&](int t, int buf) {
    int k0 = t * 32;
#pragma unroll
    for (int i = 0; i < 2; i++) {
      int rb = wv * 32 + i * 16;            // wave-uniform row base
      GLDS16(Ag + (size_t)(rb + rsub) * lda + k0 + lk * 8, &As[buf][rb * 32]);
      if constexpr (MODE != 4)
        GLDS16(Wg16 + (size_t)(rb + rsub) * ldw + k0 + lk * 8, &Bs[buf][rb * 32]);
    }
  };
  auto LOADW = [&](int t) {                 // MODE 4: coalesced f32 W load
    int k0 = t * 32;
#pragma unroll
    for (int i = 0; i < 2; i++) {
      const float* wp = Wg32 + (size_t)(wv * 32 + i * 16 + rsub) * ldw + k0 + sl * 8;
      rbf[i][0] = *(const float4*)wp;
      rbf[i][1] = *(const float4*)(wp + 4);
    }
  };
  auto WRITEW = [&](int buf) {              // MODE 4: write to swz layout
#pragma unroll
    for (int i = 0; i < 2; i++) {
      int rloc = wv * 32 + i * 16 + rsub;
      short8 pk;
      pk[0] = (short)f2bf(rbf[i][0].x); pk[1] = (short)f2bf(rbf[i][0].y);
      pk[2] = (short)f2bf(rbf[i][0].z); pk[3] = (short)f2bf(rbf[i][0].w);
      pk[4] = (short)f2bf(rbf[i][1].x); pk[5] = (short)f2bf(rbf[i][1].y);
      pk[6] = (short)f2bf(rbf[i][1].z); pk[7] = (short)f2bf(rbf[i][1].w);
      *(short8*)&Bs[buf][rloc * 32 + (sl ^ ((rsub >> 1) & 3)) * 8] = pk;
    }
  };

  int NT = K >> 5;   // K-steps of 32 (all K are multiples of 32)
  int ksw = (c >> 1) & 3;   // read-side kslot swizzle for this lane's rows

  if constexpr (MODE == 4) {
    // ---- 2-buffer drain schedule (lin head, small share of runtime) ----
    STAGE(0, 0);
    LOADW(0);
    WRITEW(0);
    asm volatile("s_waitcnt vmcnt(0) lgkmcnt(0)" ::: "memory");
    __builtin_amdgcn_s_barrier();
    int cur = 0;
    for (int t = 0; t < NT; ++t) {
      short8 afr[4], bfr[4];
#pragma unroll
      for (int mt2 = 0; mt2 < 4; mt2++)
        afr[mt2] = *(const short8*)&As[cur][(wr * 64 + mt2 * 16 + c) * 32 + (q ^ ksw) * 8];
#pragma unroll
      for (int nt2 = 0; nt2 < 4; nt2++)
        bfr[nt2] = *(const short8*)&Bs[cur][(wc * 64 + nt2 * 16 + c) * 32 + (q ^ ksw) * 8];
      asm volatile("s_waitcnt lgkmcnt(0)" ::: "memory");
      __builtin_amdgcn_sched_barrier(0);
      __builtin_amdgcn_s_barrier();
      if (t + 1 < NT) { STAGE(t + 1, cur ^ 1); LOADW(t + 1); WRITEW(cur ^ 1); }
      __builtin_amdgcn_sched_barrier(0);
#pragma unroll
      for (int mt2 = 0; mt2 < 4; mt2++)
#pragma unroll
        for (int nt2 = 0; nt2 < 4; nt2++)
          acc[mt2][nt2] = __builtin_amdgcn_mfma_f32_16x16x32_bf16(
              afr[mt2], bfr[nt2], acc[mt2][nt2], 0, 0, 0);
      if (t + 1 < NT) {
        asm volatile("s_waitcnt vmcnt(0) lgkmcnt(0)" ::: "memory");
        __builtin_amdgcn_s_barrier();
        cur ^= 1;
      }
    }
  } else {
    // ---- triple-buffer, 1 barrier per K-step ----
    STAGE(0, 0);
    if (NT > 1) {
      STAGE(1, 1);
      asm volatile("s_waitcnt vmcnt(4)" ::: "memory");   // tile 0 complete
    } else {
      asm volatile("s_waitcnt vmcnt(0)" ::: "memory");
    }
    __builtin_amdgcn_s_barrier();

    int cb = 0, sb = 2;   // current buf = t%3, stage buf = (t+2)%3
    for (int t = 0; t < NT; ++t) {
      short8 afr[4], bfr[4];
#pragma unroll
      for (int mt2 = 0; mt2 < 4; mt2++)
        afr[mt2] = *(const short8*)&As[cb][(wr * 64 + mt2 * 16 + c) * 32 + (q ^ ksw) * 8];
#pragma unroll
      for (int nt2 = 0; nt2 < 4; nt2++)
        bfr[nt2] = *(const short8*)&Bs[cb][(wc * 64 + nt2 * 16 + c) * 32 + (q ^ ksw) * 8];
      if (t + 2 < NT) STAGE(t + 2, sb);    // different buffer than any reader
      __builtin_amdgcn_sched_barrier(0);
#pragma unroll
      for (int mt2 = 0; mt2 < 4; mt2++)
#pragma unroll
        for (int nt2 = 0; nt2 < 4; nt2++)
          acc[mt2][nt2] = __builtin_amdgcn_mfma_f32_16x16x32_bf16(
              afr[mt2], bfr[nt2], acc[mt2][nt2], 0, 0, 0);
      if (t + 1 < NT) {
        if (t + 2 < NT)
          asm volatile("s_waitcnt vmcnt(4)" ::: "memory");  // t+1 done; t+2 in flight
        else
          asm volatile("s_waitcnt vmcnt(0)" ::: "memory");
        __builtin_amdgcn_s_barrier();                       // the ONLY barrier
      }
      cb = (cb == 2) ? 0 : cb + 1;
      sb = (sb == 2) ? 0 : sb + 1;
    }
  }

  // ---- epilogue ----
#pragma unroll
  for (int mt2 = 0; mt2 < 4; mt2++) {
    int row0 = mBase + wr * 64 + mt2 * 16 + q * 4;
#pragma unroll
    for (int nt2 = 0; nt2 < 4; nt2++) {
      int col = nBase + wc * 64 + nt2 * 16 + c;
      float bv = (MODE == 0 || MODE == 1 || MODE == 3) ? bias[col] : 0.f;
      f32x4 v = acc[mt2][nt2];
#pragma unroll
      for (int e = 0; e < 4; e++) {
        int row = row0 + e;
        float x = v[e] + bv;
        if (MODE == 0) x = fminf(fmaxf(x, 0.f), 6.f);
        if (MODE == 3) x += res[(size_t)row * N + col];
        if (MODE == 0 || MODE == 2) outU[(size_t)row * N + col] = f2bf(x);
        else                        outF[(size_t)row * N + col] = x;
      }
    }
  }
}

// ---------------------------------------------------------------------------
// Bucket LUT: lut[i][j] (u8, stride 224) = rp bucket 0..48 for j<196, 49
// (sentinel -> Rw[..][49] = -inf) for j in [196,224). Same for all (b,h).
// ---------------------------------------------------------------------------
__global__ __launch_bounds__(224) void blut_k(uint8_t* __restrict__ lut)
{
  int i = blockIdx.x;          // 0..195
  int j = threadIdx.x;         // 0..223
  uint8_t v = 49;
  if (j < 196) {
    int ri = i / 14, ci = i - ri * 14;
    int rj = j / 14, cj = j - rj * 14;
    int dr = ri - rj, dc = ci - cj;
    int adr = dr < 0 ? -dr : dr, adc = dc < 0 ? -dc : dc;
    int tr = adr <= 1 ? adr : (adr <= 3 ? 2 : 3);
    int tc = adc <= 1 ? adc : (adc <= 3 ? 2 : 3);
    int fr = dr < 0 ? -tr : tr, fc = dc < 0 ? -tc : tc;
    v = (uint8_t)(fr * 7 + fc + 24);
  }
  lut[i * 224 + j] = v;
}

// ---------------------------------------------------------------------------
// Fused attention per (b,h), flash-style over 7 j-chunks of 32, 2-tile ILP.
// (r19/r20 best: exp2 domain via raw __builtin_amdgcn_exp2f)
// ---------------------------------------------------------------------------
__global__ __launch_bounds__(256) void attn_k(
    const u16* __restrict__ QKV, const float* __restrict__ tabG,
    const uint8_t* __restrict__ lutG, u16* __restrict__ AO)
{
  __shared__ __align__(16) u16 Ks[4 * 196 * 8];      // [s][j][e] K fragments
  __shared__ __align__(16) u16 Vt[32 * 228];         // [d][j], pad j>=196 zero
  __shared__ __align__(16) u16 Pc4[4][2][512];       // per-wave, per-tile P chunk
  __shared__ __align__(16) u16 Ts[49 * 32];          // rpe table, [t][k] bf16
  __shared__ __align__(16) u16 Rw4[4][2][16 * 50];   // per-wave, per-tile rpe
  int bh = blockIdx.x; int b = bh / NH_, h = bh % NH_;
  int tid = threadIdx.x;
  int wv = tid >> 6, ln = tid & 63;
  int q = ln >> 4, c = ln & 15;
  size_t rowbase = (size_t)b * NPOS * 1152 + h * 32;

  // ---- stage K fragments via global_load_lds (wave-uniform dest) ----
  for (int cb = wv * 64; cb < 784; cb += 256) {
    int ch = cb + ln;
    if (ch < 784) {
      int s = ch / 196, j = ch - s * 196;
      GLDS16(QKV + rowbase + 384 + (size_t)j * 1152 + s * 8, &Ks[cb * 8]);
    }
  }
  // ---- stage rpe table transposed to [t][k] bf16 (once per block) ----
  for (int t = tid; t < 49 * 32; t += 256) {
    int tt = t >> 5, k = t & 31;
    Ts[t] = f2bf(tabG[k * 49 + tt]);
  }
  // ---- stage V transposed (vectorized) ----
  for (int t = tid; t < 784; t += 256) {
    int nn = t >> 2, d0 = (t & 3) * 8;
    short8 v = *(const short8*)(QKV + rowbase + 768 + (size_t)nn * 1152 + d0);
#pragma unroll
    for (int j = 0; j < 8; j++) Vt[(d0 + j) * 228 + nn] = (u16)v[j];
  }
  for (int t = tid; t < 32 * 32; t += 256) {
    int d = t >> 5, jj = 196 + (t & 31);
    Vt[d * 228 + jj] = 0;
  }
  __syncthreads();

  for (int it = 0; it < 2; ++it) {
    int mtA = wv + it * 8;                 // always < 13 (wv<=3 -> <=11)
    bool vB = (mtA + 4) < 13;
    int mbx[2];
    mbx[0] = mtA * 16;
    mbx[1] = (vB ? (mtA + 4) : 12) * 16;   // clamp; discarded if !vB

    short8 afrag[2];
    int i0x[2], lutOff[2][4];
#pragma unroll
    for (int x = 0; x < 2; x++) {
      int irow = mbx[x] + c; if (irow > 195) irow = 195;
      afrag[x] = *(const short8*)(QKV + rowbase + (size_t)irow * 1152 + q * 8);
      i0x[x] = mbx[x] + q * 4;
#pragma unroll
      for (int e = 0; e < 4; e++) {
        int i = i0x[x] + e; if (i > 195) i = 195;
        lutOff[x][e] = i * 224;
      }
    }
    int rwOff[4];
#pragma unroll
    for (int e = 0; e < 4; e++) rwOff[e] = (q * 4 + e) * 50;

    // ---- rpe scores via MFMA -> Rw, exp2 domain (SCALE2) ----
#pragma unroll
    for (int nt = 0; nt < 4; nt++) {
      int t = nt * 16 + c;
      int tt = t < 49 ? t : 48;
      short8 tb = *(const short8*)&Ts[tt * 32 + q * 8];
#pragma unroll
      for (int x = 0; x < 2; x++) {
        f32x4 z = {0.f, 0.f, 0.f, 0.f};
        f32x4 rr = __builtin_amdgcn_mfma_f32_16x16x32_bf16(afrag[x], tb, z, 0, 0, 0);
        if (t < 49) {
#pragma unroll
          for (int e = 0; e < 4; e++)
            Rw4[wv][x][rwOff[e] + t] = f2bf(rr[e] * SCALE2);
        }
      }
    }
    if (c == 0) {
#pragma unroll
      for (int x = 0; x < 2; x++)
#pragma unroll
        for (int e = 0; e < 4; e++)
          Rw4[wv][x][rwOff[e] + 49] = 0xFF80;   // bf16 -inf
    }

    float mr[2] = {-INFINITY, -INFINITY};
    float l4[2][4] = {{0.f,0.f,0.f,0.f},{0.f,0.f,0.f,0.f}};
    f32x4 oacc[2][2];
#pragma unroll
    for (int x = 0; x < 2; x++) {
      oacc[x][0] = (f32x4){0.f, 0.f, 0.f, 0.f};
      oacc[x][1] = (f32x4){0.f, 0.f, 0.f, 0.f};
    }

    // ---- online softmax over 7 chunks of 32 j, two tiles interleaved ----
    for (int ck = 0; ck < 7; ck++) {
      // shared K fragments for both tiles
      short8 bfr[2];
#pragma unroll
      for (int t = 0; t < 2; t++) {
        int j = (ck * 2 + t) * 16 + c;
        int jc = j > 195 ? 195 : j;
        bfr[t] = *(const short8*)&Ks[(q * 196 + jc) * 8];
      }
      f32x4 s01[2][2];
#pragma unroll
      for (int x = 0; x < 2; x++) {
        f32x4 z = {0.f, 0.f, 0.f, 0.f};
        s01[x][0] = __builtin_amdgcn_mfma_f32_16x16x32_bf16(afrag[x], bfr[0], z, 0, 0, 0);
        s01[x][1] = __builtin_amdgcn_mfma_f32_16x16x32_bf16(afrag[x], bfr[1], z, 0, 0, 0);
      }
      // bucket LUT loads -> Rw gather (mask folded in via sentinel)
      uint8_t bk[2][2][4];
#pragma unroll
      for (int t = 0; t < 2; t++) {
        int jj = ck * 32 + t * 16 + c;
#pragma unroll
        for (int x = 0; x < 2; x++)
#pragma unroll
          for (int e = 0; e < 4; e++) bk[x][t][e] = lutG[lutOff[x][e] + jj];
      }
#pragma unroll
      for (int x = 0; x < 2; x++)
#pragma unroll
        for (int t = 0; t < 2; t++)
#pragma unroll
          for (int e = 0; e < 4; e++)
            s01[x][t][e] = s01[x][t][e] * SCALE2 + bf2f(Rw4[wv][x][rwOff[e] + bk[x][t][e]]);

      // per-tile shared chunk max + rescale + raw exp2 + P store (branch-free)
#pragma unroll
      for (int x = 0; x < 2; x++) {
        float mc = s01[x][0][0];
#pragma unroll
        for (int t = 0; t < 2; t++)
#pragma unroll
          for (int e = 0; e < 4; e++) mc = fmaxf(mc, s01[x][t][e]);
#pragma unroll
        for (int o = 1; o < 16; o <<= 1) mc = fmaxf(mc, __shfl_xor(mc, o, 64));
        float mn = fmaxf(mr[x], mc);
        float sc = __builtin_amdgcn_exp2f(mr[x] - mn);
        mr[x] = mn;
#pragma unroll
        for (int t = 0; t < 2; t++)
#pragma unroll
          for (int e = 0; e < 4; e++) s01[x][t][e] = __builtin_amdgcn_exp2f(s01[x][t][e] - mn);
#pragma unroll
        for (int e = 0; e < 4; e++) {
          l4[x][e] = l4[x][e] * sc + s01[x][0][e] + s01[x][1][e];
          oacc[x][0][e] *= sc; oacc[x][1][e] *= sc;
        }
#pragma unroll
        for (int t = 0; t < 2; t++) {
          int sl2 = t * 2 + (c >> 3);
#pragma unroll
          for (int e = 0; e < 4; e++) {
            union { float f; uint32_t u; } pv; pv.f = s01[x][t][e];
            Pc4[wv][x][(sl2 * 16 + q * 4 + e) * 8 + (c & 7)] = (u16)(pv.u >> 16);
          }
        }
      }
      // PV: shared V fragment, 2 MFMAs per tile
#pragma unroll
      for (int n2 = 0; n2 < 2; n2++) {
        short8 vb = *(const short8*)&Vt[(n2 * 16 + c) * 228 + ck * 32 + q * 8];
#pragma unroll
        for (int x = 0; x < 2; x++) {
          short8 pa = *(const short8*)&Pc4[wv][x][(q * 16 + c) * 8];
          oacc[x][n2] = __builtin_amdgcn_mfma_f32_16x16x32_bf16(pa, vb, oacc[x][n2], 0, 0, 0);
        }
      }
    }

    // ---- final 1/l and store per tile ----
#pragma unroll
    for (int x = 0; x < 2; x++) {
      if (x == 1 && !vB) continue;
      float inv[4];
#pragma unroll
      for (int e = 0; e < 4; e++) {
        float s2 = l4[x][e];
#pragma unroll
        for (int o = 1; o < 16; o <<= 1) s2 += __shfl_xor(s2, o, 64);
        inv[e] = 1.f / s2;
      }
#pragma unroll
      for (int n2 = 0; n2 < 2; n2++) {
#pragma unroll
        for (int e = 0; e < 4; e++) {
          int i = i0x[x] + e;
          if (i < 196) {
            int d = n2 * 16 + c;
            AO[((size_t)b * NPOS + i) * DM + h * 32 + d] = f2bf(oacc[x][n2][e] * inv[e]);
          }
        }
      }
    }
  }
}

// ---------------------------------------------------------------------------
// x (B, CIN, HW, HW) f32  ->  A_t (B*NPOS, CIN) bf16
// ---------------------------------------------------------------------------
__global__ __launch_bounds__(256) void transpose_cast_k(
    const float* __restrict__ x, u16* __restrict__ At)
{
  __shared__ float t[32][33];
  int c0 = blockIdx.x * 32, n0 = blockIdx.y * 32, b = blockIdx.z;
  int tx = threadIdx.x, ty = threadIdx.y;
  const float* xb = x + (size_t)b * CIN * NPOS;
#pragma unroll
  for (int i = 0; i < 4; i++) {
    int cc = c0 + ty + i * 8, nn = n0 + tx;
    t[ty + i * 8][tx] = (nn < NPOS) ? xb[(size_t)cc * NPOS + nn] : 0.f;
  }
  __syncthreads();
  u16* Ab = At + (size_t)b * NPOS * CIN;
#pragma unroll
  for (int i = 0; i < 4; i++) {
    int nn = n0 + ty + i * 8, cc = c0 + tx;
    if (nn < NPOS) Ab[(size_t)nn * CIN + cc] = f2bf(t[tx][ty + i * 8]);
  }
}

// ---------------------------------------------------------------------------
// depthwise 3x3 SAME conv + bias + identity residual (fp32)
// ---------------------------------------------------------------------------
__global__ __launch_bounds__(256) void conv_res_k(
    const float* __restrict__ T0, const float* __restrict__ pcw,
    const float* __restrict__ pcb, float* __restrict__ T1)
{
  int idx = blockIdx.x * 256 + threadIdx.x;
  if (idx >= B_ * NPOS * 96) return;
  int d4 = idx % 96; int rem = idx / 96;
  int n = rem % NPOS; int b = rem / NPOS;
  int hh = n / 14, ww = n % 14;
  int d0 = d4 * 4;
  float w9[4][9];
#pragma unroll
  for (int j = 0; j < 4; j++)
#pragma unroll
    for (int t = 0; t < 9; t++) w9[j][t] = pcw[(d0 + j) * 9 + t];
  const float* base = T0 + (size_t)b * NPOS * DM;
  float4 ctr = *(const float4*)(base + (size_t)n * DM + d0);
  float ax = ctr.x + pcb[d0], ay = ctr.y + pcb[d0 + 1];
  float az = ctr.z + pcb[d0 + 2], aw = ctr.w + pcb[d0 + 3];
#pragma unroll
  for (int kh = 0; kh < 3; kh++) {
    int h2 = hh + kh - 1;
    if (h2 < 0 || h2 >= 14) continue;
#pragma unroll
    for (int kw = 0; kw < 3; kw++) {
      int w2 = ww + kw - 1;
      if (w2 < 0 || w2 >= 14) continue;
      float4 v = *(const float4*)(base + (size_t)(h2 * 14 + w2) * DM + d0);
      int t = kh * 3 + kw;
      ax += v.x * w9[0][t]; ay += v.y * w9[1][t];
      az += v.z * w9[2][t]; aw += v.w * w9[3][t];
    }
  }
  float4 o = {ax, ay, az, aw};
  *(float4*)(T1 + (size_t)b * NPOS * DM + (size_t)n * DM + d0) = o;
}

// ---------------------------------------------------------------------------
// LayerNorm(384) f32 -> bf16, one wave per row (float2-vectorized)
// ---------------------------------------------------------------------------
__global__ __launch_bounds__(256) void ln_k(
    const float* __restrict__ in, const float* __restrict__ w,
    const float* __restrict__ bb, u16* __restrict__ out)
{
  int row = blockIdx.x * 4 + (threadIdx.x >> 6);
  int ln = threadIdx.x & 63;
  const float2* r = (const float2*)(in + (size_t)row * DM);
  float2 v[3]; float s = 0.f, sq = 0.f;
#pragma unroll
  for (int j = 0; j < 3; j++) {
    v[j] = r[ln + 64 * j];
    s += v[j].x + v[j].y; sq += v[j].x * v[j].x + v[j].y * v[j].y;
  }
#pragma unroll
  for (int o = 1; o < 64; o <<= 1) { s += __shfl_xor(s, o, 64); sq += __shfl_xor(sq, o, 64); }
  float mu = s * (1.f / 384.f);
  float var = sq * (1.f / 384.f) - mu * mu;
  float rs = rsqrtf(var + 1e-5f);
  uint32_t* orow = (uint32_t*)(out + (size_t)row * DM);
#pragma unroll
  for (int j = 0; j < 3; j++) {
    int d = (ln + 64 * j) * 2;
    float a = (v[j].x - mu) * rs * w[d] + bb[d];
    float bq = (v[j].y - mu) * rs * w[d + 1] + bb[d + 1];
    orow[ln + 64 * j] = (uint32_t)f2bf(a) | ((uint32_t)f2bf(bq) << 16);
  }
}

// ---------------------------------------------------------------------------
// BN1 over (batch, dmodel) per position n: two-stage stats
// ---------------------------------------------------------------------------
__global__ __launch_bounds__(256) void bn1_partial_k(
    const float* __restrict__ T3, float* __restrict__ part)
{
  int n = blockIdx.x >> 3, g = blockIdx.x & 7;
  int tid = threadIdx.x;
  float s = 0.f, sq = 0.f;
  for (int b2 = g * 16; b2 < g * 16 + 16; b2++) {
    const float* p = T3 + ((size_t)b2 * NPOS + n) * DM;
    for (int d = tid; d < DM; d += 256) { float v = p[d]; s += v; sq += v * v; }
  }
#pragma unroll
  for (int o = 1; o < 64; o <<= 1) { s += __shfl_xor(s, o, 64); sq += __shfl_xor(sq, o, 64); }
  __shared__ float ls[4], lq[4];
  int wv = tid >> 6, ln = tid & 63;
  if (ln == 0) { ls[wv] = s; lq[wv] = sq; }
  __syncthreads();
  if (tid == 0) {
    part[blockIdx.x * 2]     = ls[0] + ls[1] + ls[2] + ls[3];
    part[blockIdx.x * 2 + 1] = lq[0] + lq[1] + lq[2] + lq[3];
  }
}

__global__ __launch_bounds__(256) void bn1_finish_k(
    const float* __restrict__ part, const float* __restrict__ bw,
    const float* __restrict__ bbb, float* __restrict__ scaleArr,
    float* __restrict__ shiftArr)
{
  int n = threadIdx.x;
  if (n >= NPOS) return;
  float S = 0.f, Q = 0.f;
#pragma unroll
  for (int g = 0; g < 8; g++) { S += part[(n * 8 + g) * 2]; Q += part[(n * 8 + g) * 2 + 1]; }
  float mu = S / 49152.f;
  float var = Q / 49152.f - mu * mu;
  float rs = rsqrtf(var + 2e-5f);
  float sc = rs * bw[n];
  scaleArr[n] = sc;
  shiftArr[n] = bbb[n] - mu * sc;
}

__global__ __launch_bounds__(256) void bn1_apply_k(
    const float* __restrict__ T3, const float* __restrict__ scaleArr,
    const float* __restrict__ shiftArr, u16* __restrict__ outb)
{
  int idx = blockIdx.x * 256 + threadIdx.x;           // float4 index
  if (idx >= MT * DM / 4) return;
  int n = (idx / 96) % NPOS;
  float4 v = *(const float4*)(T3 + (size_t)idx * 4);
  float sc = scaleArr[n], sh = shiftArr[n];
  uint32_t p0 = (uint32_t)f2bf(v.x * sc + sh) | ((uint32_t)f2bf(v.y * sc + sh) << 16);
  uint32_t p1 = (uint32_t)f2bf(v.z * sc + sh) | ((uint32_t)f2bf(v.w * sc + sh) << 16);
  ((uint2*)outb)[idx] = make_uint2(p0, p1);
}

// ---------------------------------------------------------------------------
// split-K reduce for lin head + bias
// ---------------------------------------------------------------------------
__global__ __launch_bounds__(256) void lin_reduce_k(
    const float* __restrict__ part, const float* __restrict__ lb,
    float* __restrict__ y)
{
  int idx = blockIdx.x * 256 + threadIdx.x;
  if (idx >= 128 * DM) return;
  int col = idx % DM;
  float s = lb[col];
#pragma unroll
  for (int sp = 0; sp < 49; sp++) s += part[(size_t)sp * (128 * DM) + idx];
  y[idx] = s;
}

// ---------------------------------------------------------------------------
// BN2 over batch (128) per feature col, in-place on y
// ---------------------------------------------------------------------------
__global__ __launch_bounds__(64) void bn2_k(
    float* __restrict__ y, const float* __restrict__ w,
    const float* __restrict__ bb)
{
  int col = blockIdx.x; int ln = threadIdx.x;
  float v0 = y[(size_t)ln * DM + col];
  float v1 = y[(size_t)(ln + 64) * DM + col];
  float s = v0 + v1, sq = v0 * v0 + v1 * v1;
#pragma unroll
  for (int o = 1; o < 64; o <<= 1) { s += __shfl_xor(s, o, 64); sq += __shfl_xor(sq, o, 64); }
  float mu = s / 128.f;
  float var = sq / 128.f - mu * mu;
  float rs = rsqrtf(var + 2e-5f);
  float sc = rs * w[col], sh = bb[col] - mu * sc;
  y[(size_t)ln * DM + col] = v0 * sc + sh;
  y[(size_t)(ln + 64) * DM + col] = v1 * sc + sh;
}

// ---------------------------------------------------------------------------
// merged f32 -> bf16 cast for the six small weight matrices
// ---------------------------------------------------------------------------
__global__ __launch_bounds__(256) void castall_k(
    const float* __restrict__ s0, u16* __restrict__ d0,
    const float* __restrict__ s1, u16* __restrict__ d1,
    const float* __restrict__ s2, u16* __restrict__ d2,
    const float* __restrict__ s3, u16* __restrict__ d3,
    const float* __restrict__ s4, u16* __restrict__ d4,
    const float* __restrict__ s5, u16* __restrict__ d5)
{
  const int b0 = 262144, b1 = b0 + 98304, b2 = b1 + 110592,
            b3 = b2 + 36864, b4 = b3 + 147456, b5 = b4 + 147456; // 802816
  int idx = blockIdx.x * 256 + threadIdx.x;
  int stride = gridDim.x * 256;
  for (; idx < b5; idx += stride) {
    const float* s; u16* d; int l;
    if      (idx < b0) { s = s0; d = d0; l = idx; }
    else if (idx < b1) { s = s1; d = d1; l = idx - b0; }
    else if (idx < b2) { s = s2; d = d2; l = idx - b1; }
    else if (idx < b3) { s = s3; d = d3; l = idx - b2; }
    else if (idx < b4) { s = s4; d = d4; l = idx - b3; }
    else               { s = s5; d = d5; l = idx - b4; }
    float4 v = *(const float4*)(s + (size_t)l * 4);
    uint32_t p0 = (uint32_t)f2bf(v.x) | ((uint32_t)f2bf(v.y) << 16);
    uint32_t p1 = (uint32_t)f2bf(v.z) | ((uint32_t)f2bf(v.w) << 16);
    ((uint2*)d)[l] = make_uint2(p0, p1);
  }
}

// ---------------------------------------------------------------------------
// Orchestration
// ---------------------------------------------------------------------------
extern "C" void kernel_launch(void* const* d_in, const int* in_sizes, int n_in,
                              void* d_out, int out_size, void* d_ws, size_t ws_size,
                              hipStream_t stream)
{
  (void)in_sizes; (void)n_in; (void)out_size;
  const float* x    = (const float*)d_in[0];
  const float* fc1w = (const float*)d_in[1];
  const float* fc1b = (const float*)d_in[2];
  const float* fc2w = (const float*)d_in[3];
  const float* fc2b = (const float*)d_in[4];
  const float* pcw  = (const float*)d_in[5];
  const float* pcb  = (const float*)d_in[6];
  const float* ln1w = (const float*)d_in[7];
  const float* ln1b = (const float*)d_in[8];
  const float* qkvw = (const float*)d_in[9];
  const float* rpet = (const float*)d_in[10];
  const float* projw= (const float*)d_in[11];
  const float* projb= (const float*)d_in[12];
  const float* ln2w = (const float*)d_in[13];
  const float* ln2b = (const float*)d_in[14];
  const float* m1w  = (const float*)d_in[15];
  const float* m1b  = (const float*)d_in[16];
  const float* m2w  = (const float*)d_in[17];
  const float* m2b  = (const float*)d_in[18];
  const float* bn1w = (const float*)d_in[19];
  const float* bn1b = (const float*)d_in[20];
  const float* linw = (const float*)d_in[21];
  const float* linb = (const float*)d_in[22];
  const float* bn2w = (const float*)d_in[23];
  const float* bn2b = (const float*)d_in[24];
  float* y = (float*)d_out;

  // -------- aliased workspace layout (regions share by liveness) ----------
  const size_t RA = 0;                      // At / MLP1
  const size_t RB = 77070336;               // U / QKV / T3nb
  const size_t RC = RB + 57802752;          // H / AO / H2
  const size_t RD = RC + 19267584;          // T0 / T2
  const size_t RE = RD + 38535168;          // T1 / T3
  const size_t RF = RE + 38535168;          // PART (lin split-K)
  const size_t RG = RF + 9633792;           // small bf16 weights
  const size_t RS = RG + 6422528;           // bn1 scale/shift + partials + lut
  const size_t NEED = RS + 2048 + 16384 + 45056;
  if (ws_size < NEED) return;

  char* ws = (char*)d_ws;
  u16*   At    = (u16*)(ws + RA);
  u16*   MLP1  = (u16*)(ws + RA);
  u16*   U     = (u16*)(ws + RB);
  u16*   QKV   = (u16*)(ws + RB);
  u16*   T3nb  = (u16*)(ws + RB);
  u16*   H     = (u16*)(ws + RC);
  u16*   AO    = (u16*)(ws + RC);
  u16*   H2    = (u16*)(ws + RC);
  float* T0    = (float*)(ws + RD);
  float* T2    = (float*)(ws + RD);
  float* T1    = (float*)(ws + RE);
  float* T3    = (float*)(ws + RE);
  float* PART  = (float*)(ws + RF);
  u16*   wb_fc1 = (u16*)(ws + RG);
  u16*   wb_fc2 = wb_fc1 + 1048576;
  u16*   wb_qkv = wb_fc2 + 393216;
  u16*   wb_proj= wb_qkv + 442368;
  u16*   wb_m1  = wb_proj + 147456;
  u16*   wb_m2  = wb_m1 + 589824;
  float* bnS   = (float*)(ws + RS);
  float* bnSh  = bnS + 196;
  float* bnP   = (float*)(ws + RS + 2048);
  uint8_t* blut = (uint8_t*)(ws + RS + 2048 + 16384);

  // weight casts (f32 -> bf16), one merged kernel + bucket LUT
  castall_k<<<1024, 256, 0, stream>>>(fc1w, wb_fc1, fc2w, wb_fc2, qkvw, wb_qkv,
                                      projw, wb_proj, m1w, wb_m1, m2w, wb_m2);
  blut_k<<<196, 224, 0, stream>>>(blut);

  // x (B,CIN,N) -> At (B*N, CIN) bf16
  transpose_cast_k<<<dim3(32, 7, 128), dim3(32, 8), 0, stream>>>(x, At);

  // embed fc1: U = relu6(At @ fc1w^T + b)   [25088 x 1024]
  gemm_k<0><<<196 * 8, 256, 0, stream>>>(At, wb_fc1, fc1b, nullptr, U,
                                          MT, 1024, 1024, 1024, 1024, 8, 0);
  // embed fc2: T0 = U @ fc2w^T + b          [25088 x 384] f32
  gemm_k<1><<<196 * 3, 256, 0, stream>>>(U, wb_fc2, fc2b, nullptr, T0,
                                          MT, 384, 1024, 1024, 1024, 3, 0);
  // depthwise conv + bias + residual -> T1
  conv_res_k<<<(B_ * NPOS * 96 + 255) / 256, 256, 0, stream>>>(T0, pcw, pcb, T1);
  // LN1 -> H (bf16)
  ln_k<<<MT / 4, 256, 0, stream>>>(T1, ln1w, ln1b, H);
  // qkv: QKV = H @ qkvw^T (no bias)          [25088 x 1152] bf16
  gemm_k<2><<<196 * 9, 256, 0, stream>>>(H, wb_qkv, nullptr, nullptr, QKV,
                                          MT, 1152, 384, 384, 384, 9, 0);
  // fused attention (rpe in-kernel, flash-style, LUT bias, 2-tile ILP) -> AO
  attn_k<<<1536, 256, 0, stream>>>(QKV, rpet, blut, AO);
  // proj + residual(T1) -> T2 (f32)
  gemm_k<3><<<196 * 3, 256, 0, stream>>>(AO, wb_proj, projb, T1, T2,
                                          MT, 384, 384, 384, 384, 3, 0);
  // LN2 -> H2 (bf16)
  ln_k<<<MT / 4, 256, 0, stream>>>(T2, ln2w, ln2b, H2);
  // mlp fc1: MLP1 = relu6(H2 @ m1w^T + b)    [25088 x 1536] bf16
  gemm_k<0><<<196 * 12, 256, 0, stream>>>(H2, wb_m1, m1b, nullptr, MLP1,
                                           MT, 1536, 384, 384, 384, 12, 0);
  // mlp fc2 + residual(T2) -> T3 (f32)
  gemm_k<3><<<196 * 3, 256, 0, stream>>>(MLP1, wb_m2, m2b, T2, T3,
                                          MT, 384, 1536, 1536, 1536, 3, 0);
  // BN1 (per position) -> T3nb (bf16)
  bn1_partial_k<<<196 * 8, 256, 0, stream>>>(T3, bnP);
  bn1_finish_k<<<1, 256, 0, stream>>>(bnP, bn1w, bn1b, bnS, bnSh);
  bn1_apply_k<<<(MT * DM / 4 + 255) / 256, 256, 0, stream>>>(T3, bnS, bnSh, T3nb);
  // lin head: y = T3nb(128 x 75264) @ linw^T, split-K 49 x 1536 (W f32 direct)
  gemm_k<4><<<3 * 49, 256, 0, stream>>>(T3nb, linw, nullptr, nullptr, PART,
                                         128, 384, 1536, 75264, 75264, 3, 1536);
  lin_reduce_k<<<192, 256, 0, stream>>>(PART, linb, y);
  // BN2 (per feature over batch), in place on d_out
  bn2_k<<<384, 64, 0, stream>>>(y, bn2w, bn2b);
}

// Round 23
// 545.999 us; speedup vs baseline: 1.0491x; 1.0022x over previous
//
#include <hip/hip_runtime.h>
#include <cstdint>

// ---------------------------------------------------------------------------
// Problem constants
// ---------------------------------------------------------------------------
#define B_    128
#define CIN   1024
#define NPOS  196          // 14*14
#define DM    384
#define NH_   12
#define HD_   32
#define DFF_  1536
#define MT    25088        // B_*NPOS
#define SCALE_Q 0.17677669529663687f   // 1/sqrt(32)
#define SCALE2  0.25503485810335155f   // SCALE_Q * log2(e)  (exp2 domain)

typedef unsigned short u16;
typedef __attribute__((ext_vector_type(8))) short  short8;   // 8 bf16 (4 VGPR)
typedef __attribute__((ext_vector_type(4))) float  f32x4;    // MFMA C/D

__device__ __forceinline__ u16 f2bf(float f) {
  union { float f; uint32_t u; } v; v.f = f;
  uint32_t u = v.u;
  return (u16)((u + 0x7fffu + ((u >> 16) & 1u)) >> 16);
}
__device__ __forceinline__ float bf2f(u16 h) {
  union { uint32_t u; float f; } v; v.u = ((uint32_t)h) << 16;
  return v.f;
}

#define GLDS16(g, l)                                                           \
  __builtin_amdgcn_global_load_lds(                                            \
      (const __attribute__((address_space(1))) void*)(g),                      \
      (__attribute__((address_space(3))) void*)(l), 16, 0, 0)

// ---------------------------------------------------------------------------
// Generic bf16 MFMA GEMM (r20 best: triple-buffer, 1 barrier/K-step; GLDS
// with pre-swizzled source; counted vmcnt; XCD-chunked bijective swizzle).
// MODE: 0 = bias+relu6 -> bf16 | 1 = bias -> f32 | 2 = plain -> bf16
//       3 = bias+res -> f32    | 4 = split-K partial -> f32
// ---------------------------------------------------------------------------
template <int MODE>
__global__ __launch_bounds__(256) void gemm_k(
    const u16* __restrict__ A, const void* __restrict__ Wv,
    const float* __restrict__ bias, const float* __restrict__ res,
    void* __restrict__ outp,
    int M, int N, int K, int lda, int ldw, int nTN, int splitK)
{
  __shared__ __align__(16) u16 As[3][128 * 32];   // row-major [r][kphys]
  __shared__ __align__(16) u16 Bs[3][128 * 32];

  int nwg = gridDim.x;
  int bid0 = blockIdx.x;
  int qq = nwg >> 3, rr = nwg & 7;
  int xcd = bid0 & 7, idx = bid0 >> 3;
  int bid = (xcd < rr ? xcd * (qq + 1) : rr * (qq + 1) + (xcd - rr) * qq) + idx;

  int split = 0, mT, nT;
  if (MODE == 4) { split = bid / nTN; nT = bid % nTN; mT = 0; }
  else           { mT = bid / nTN;    nT = bid % nTN; }

  const u16* Ab = A + (size_t)split * splitK;
  float* outF = (float*)outp + ((MODE == 4) ? (size_t)split * (size_t)M * N : (size_t)0);
  u16*   outU = (u16*)outp;

  int tid = threadIdx.x;
  int wv = tid >> 6, ln = tid & 63;
  int q = ln >> 4, c = ln & 15;
  int wr = wv >> 1, wc = wv & 1;
  int mBase = mT * 128, nBase = nT * 128;

  f32x4 acc[4][4];
#pragma unroll
  for (int i = 0; i < 4; i++)
#pragma unroll
    for (int j = 0; j < 4; j++) acc[i][j] = (f32x4){0.f, 0.f, 0.f, 0.f};

  const u16* Ag = Ab + (size_t)mBase * lda;
  const u16*  Wg16 = (const u16*)Wv + (size_t)split * splitK + (size_t)nBase * ldw;
  const float* Wg32 = (const float*)Wv + (size_t)split * splitK + (size_t)nBase * ldw;

  int sl = ln & 3, rsub = ln >> 2;          // lane -> (phys kslot, row-in-16)
  int lk = sl ^ ((rsub >> 1) & 3);          // logical kslot this lane fetches

  float4 rbf[2][2];                         // MODE 4: raw f32 W held in regs

  auto STAGE = [&](int t, int buf) {
    int k0 = t * 32;
#pragma unroll
    for (int i = 0; i < 2; i++) {
      int rb = wv * 32 + i * 16;            // wave-uniform row base
      GLDS16(Ag + (size_t)(rb + rsub) * lda + k0 + lk * 8, &As[buf][rb * 32]);
      if constexpr (MODE != 4)
        GLDS16(Wg16 + (size_t)(rb + rsub) * ldw + k0 + lk * 8, &Bs[buf][rb * 32]);
    }
  };
  auto LOADW = [&](int t) {                 // MODE 4: coalesced f32 W load
    int k0 = t * 32;
#pragma unroll
    for (int i = 0; i < 2; i++) {
      const float* wp = Wg32 + (size_t)(wv * 32 + i * 16 + rsub) * ldw + k0 + sl * 8;
      rbf[i][0] = *(const float4*)wp;
      rbf[i][1] = *(const float4*)(wp + 4);
    }
  };
  auto WRITEW = [&](int buf) {              // MODE 4: write to swz layout
#pragma unroll
    for (int i = 0; i < 2; i++) {
      int rloc = wv * 32 + i * 16 + rsub;
      short8 pk;
      pk[0] = (short)f2bf(rbf[i][0].x); pk[1] = (short)f2bf(rbf[i][0].y);
      pk[2] = (short)f2bf(rbf[i][0].z); pk[3] = (short)f2bf(rbf[i][0].w);
      pk[4] = (short)f2bf(rbf[i][1].x); pk[5] = (short)f2bf(rbf[i][1].y);
      pk[6] = (short)f2bf(rbf[i][1].z); pk[7] = (short)f2bf(rbf[i][1].w);
      *(short8*)&Bs[buf][rloc * 32 + (sl ^ ((rsub >> 1) & 3)) * 8] = pk;
    }
  };

  int NT = K >> 5;   // K-steps of 32 (all K are multiples of 32)
  int ksw = (c >> 1) & 3;   // read-side kslot swizzle for this lane's rows

  if constexpr (MODE == 4) {
    // ---- 2-buffer drain schedule (lin head, small share of runtime) ----
    STAGE(0, 0);
    LOADW(0);
    WRITEW(0);
    asm volatile("s_waitcnt vmcnt(0) lgkmcnt(0)" ::: "memory");
    __builtin_amdgcn_s_barrier();
    int cur = 0;
    for (int t = 0; t < NT; ++t) {
      short8 afr[4], bfr[4];
#pragma unroll
      for (int mt2 = 0; mt2 < 4; mt2++)
        afr[mt2] = *(const short8*)&As[cur][(wr * 64 + mt2 * 16 + c) * 32 + (q ^ ksw) * 8];
#pragma unroll
      for (int nt2 = 0; nt2 < 4; nt2++)
        bfr[nt2] = *(const short8*)&Bs[cur][(wc * 64 + nt2 * 16 + c) * 32 + (q ^ ksw) * 8];
      asm volatile("s_waitcnt lgkmcnt(0)" ::: "memory");
      __builtin_amdgcn_sched_barrier(0);
      __builtin_amdgcn_s_barrier();
      if (t + 1 < NT) { STAGE(t + 1, cur ^ 1); LOADW(t + 1); WRITEW(cur ^ 1); }
      __builtin_amdgcn_sched_barrier(0);
#pragma unroll
      for (int mt2 = 0; mt2 < 4; mt2++)
#pragma unroll
        for (int nt2 = 0; nt2 < 4; nt2++)
          acc[mt2][nt2] = __builtin_amdgcn_mfma_f32_16x16x32_bf16(
              afr[mt2], bfr[nt2], acc[mt2][nt2], 0, 0, 0);
      if (t + 1 < NT) {
        asm volatile("s_waitcnt vmcnt(0) lgkmcnt(0)" ::: "memory");
        __builtin_amdgcn_s_barrier();
        cur ^= 1;
      }
    }
  } else {
    // ---- triple-buffer, 1 barrier per K-step ----
    STAGE(0, 0);
    if (NT > 1) {
      STAGE(1, 1);
      asm volatile("s_waitcnt vmcnt(4)" ::: "memory");   // tile 0 complete
    } else {
      asm volatile("s_waitcnt vmcnt(0)" ::: "memory");
    }
    __builtin_amdgcn_s_barrier();

    int cb = 0, sb = 2;   // current buf = t%3, stage buf = (t+2)%3
    for (int t = 0; t < NT; ++t) {
      short8 afr[4], bfr[4];
#pragma unroll
      for (int mt2 = 0; mt2 < 4; mt2++)
        afr[mt2] = *(const short8*)&As[cb][(wr * 64 + mt2 * 16 + c) * 32 + (q ^ ksw) * 8];
#pragma unroll
      for (int nt2 = 0; nt2 < 4; nt2++)
        bfr[nt2] = *(const short8*)&Bs[cb][(wc * 64 + nt2 * 16 + c) * 32 + (q ^ ksw) * 8];
      if (t + 2 < NT) STAGE(t + 2, sb);    // different buffer than any reader
      __builtin_amdgcn_sched_barrier(0);
#pragma unroll
      for (int mt2 = 0; mt2 < 4; mt2++)
#pragma unroll
        for (int nt2 = 0; nt2 < 4; nt2++)
          acc[mt2][nt2] = __builtin_amdgcn_mfma_f32_16x16x32_bf16(
              afr[mt2], bfr[nt2], acc[mt2][nt2], 0, 0, 0);
      if (t + 1 < NT) {
        if (t + 2 < NT)
          asm volatile("s_waitcnt vmcnt(4)" ::: "memory");  // t+1 done; t+2 in flight
        else
          asm volatile("s_waitcnt vmcnt(0)" ::: "memory");
        __builtin_amdgcn_s_barrier();                       // the ONLY barrier
      }
      cb = (cb == 2) ? 0 : cb + 1;
      sb = (sb == 2) ? 0 : sb + 1;
    }
  }

  // ---- epilogue ----
#pragma unroll
  for (int mt2 = 0; mt2 < 4; mt2++) {
    int row0 = mBase + wr * 64 + mt2 * 16 + q * 4;
#pragma unroll
    for (int nt2 = 0; nt2 < 4; nt2++) {
      int col = nBase + wc * 64 + nt2 * 16 + c;
      float bv = (MODE == 0 || MODE == 1 || MODE == 3) ? bias[col] : 0.f;
      f32x4 v = acc[mt2][nt2];
#pragma unroll
      for (int e = 0; e < 4; e++) {
        int row = row0 + e;
        float x = v[e] + bv;
        if (MODE == 0) x = fminf(fmaxf(x, 0.f), 6.f);
        if (MODE == 3) x += res[(size_t)row * N + col];
        if (MODE == 0 || MODE == 2) outU[(size_t)row * N + col] = f2bf(x);
        else                        outF[(size_t)row * N + col] = x;
      }
    }
  }
}

// ---------------------------------------------------------------------------
// Bucket LUT: lut[i][j] (u8, stride 224) = rp bucket 0..48 for j<196, 49
// (sentinel -> Rw[..][49] = -inf) for j in [196,224). Same for all (b,h).
// ---------------------------------------------------------------------------
__global__ __launch_bounds__(224) void blut_k(uint8_t* __restrict__ lut)
{
  int i = blockIdx.x;          // 0..195
  int j = threadIdx.x;         // 0..223
  uint8_t v = 49;
  if (j < 196) {
    int ri = i / 14, ci = i - ri * 14;
    int rj = j / 14, cj = j - rj * 14;
    int dr = ri - rj, dc = ci - cj;
    int adr = dr < 0 ? -dr : dr, adc = dc < 0 ? -dc : dc;
    int tr = adr <= 1 ? adr : (adr <= 3 ? 2 : 3);
    int tc = adc <= 1 ? adc : (adc <= 3 ? 2 : 3);
    int fr = dr < 0 ? -tr : tr, fc = dc < 0 ? -tc : tc;
    v = (uint8_t)(fr * 7 + fc + 24);
  }
  lut[i * 224 + j] = v;
}

// ---------------------------------------------------------------------------
// Fused attention per (b,h), flash-style over 7 j-chunks of 32, 2-tile ILP.
// r23: K fragments read DIRECTLY from global (L2-resident per-block slice;
//   16 rows x 64B contiguous per instruction = 16 lines, coalesced-per-row).
//   Dropping the 12.5KB Ks staging brings LDS to 38720 B -> 4 blocks/CU
//   (16 waves/CU, matching the 72-VGPR cap) — +33% TLP for this
//   chain-latency-bound kernel.
// LDS = 14592(Vt) + 8192(Pc) + 3136(Ts) + 12800(Rw) = 38720 B.
// ---------------------------------------------------------------------------
__global__ __launch_bounds__(256) void attn_k(
    const u16* __restrict__ QKV, const float* __restrict__ tabG,
    const uint8_t* __restrict__ lutG, u16* __restrict__ AO)
{
  __shared__ __align__(16) u16 Vt[32 * 228];         // [d][j], pad j>=196 zero
  __shared__ __align__(16) u16 Pc4[4][2][512];       // per-wave, per-tile P chunk
  __shared__ __align__(16) u16 Ts[49 * 32];          // rpe table, [t][k] bf16
  __shared__ __align__(16) u16 Rw4[4][2][16 * 50];   // per-wave, per-tile rpe
  int bh = blockIdx.x; int b = bh / NH_, h = bh % NH_;
  int tid = threadIdx.x;
  int wv = tid >> 6, ln = tid & 63;
  int q = ln >> 4, c = ln & 15;
  size_t rowbase = (size_t)b * NPOS * 1152 + h * 32;
  const u16* Kg = QKV + rowbase + 384;     // K base for this (b,h)

  // ---- stage rpe table transposed to [t][k] bf16 (once per block) ----
  for (int t = tid; t < 49 * 32; t += 256) {
    int tt = t >> 5, k = t & 31;
    Ts[t] = f2bf(tabG[k * 49 + tt]);
  }
  // ---- stage V transposed (vectorized) ----
  for (int t = tid; t < 784; t += 256) {
    int nn = t >> 2, d0 = (t & 3) * 8;
    short8 v = *(const short8*)(QKV + rowbase + 768 + (size_t)nn * 1152 + d0);
#pragma unroll
    for (int j = 0; j < 8; j++) Vt[(d0 + j) * 228 + nn] = (u16)v[j];
  }
  for (int t = tid; t < 32 * 32; t += 256) {
    int d = t >> 5, jj = 196 + (t & 31);
    Vt[d * 228 + jj] = 0;
  }
  __syncthreads();

  for (int it = 0; it < 2; ++it) {
    int mtA = wv + it * 8;                 // always < 13 (wv<=3 -> <=11)
    bool vB = (mtA + 4) < 13;
    int mbx[2];
    mbx[0] = mtA * 16;
    mbx[1] = (vB ? (mtA + 4) : 12) * 16;   // clamp; discarded if !vB

    short8 afrag[2];
    int i0x[2], lutOff[2][4];
#pragma unroll
    for (int x = 0; x < 2; x++) {
      int irow = mbx[x] + c; if (irow > 195) irow = 195;
      afrag[x] = *(const short8*)(QKV + rowbase + (size_t)irow * 1152 + q * 8);
      i0x[x] = mbx[x] + q * 4;
#pragma unroll
      for (int e = 0; e < 4; e++) {
        int i = i0x[x] + e; if (i > 195) i = 195;
        lutOff[x][e] = i * 224;
      }
    }
    int rwOff[4];
#pragma unroll
    for (int e = 0; e < 4; e++) rwOff[e] = (q * 4 + e) * 50;

    // ---- rpe scores via MFMA -> Rw, exp2 domain (SCALE2) ----
#pragma unroll
    for (int nt = 0; nt < 4; nt++) {
      int t = nt * 16 + c;
      int tt = t < 49 ? t : 48;
      short8 tb = *(const short8*)&Ts[tt * 32 + q * 8];
#pragma unroll
      for (int x = 0; x < 2; x++) {
        f32x4 z = {0.f, 0.f, 0.f, 0.f};
        f32x4 rr = __builtin_amdgcn_mfma_f32_16x16x32_bf16(afrag[x], tb, z, 0, 0, 0);
        if (t < 49) {
#pragma unroll
          for (int e = 0; e < 4; e++)
            Rw4[wv][x][rwOff[e] + t] = f2bf(rr[e] * SCALE2);
        }
      }
    }
    if (c == 0) {
#pragma unroll
      for (int x = 0; x < 2; x++)
#pragma unroll
        for (int e = 0; e < 4; e++)
          Rw4[wv][x][rwOff[e] + 49] = 0xFF80;   // bf16 -inf
    }

    float mr[2] = {-INFINITY, -INFINITY};
    float l4[2][4] = {{0.f,0.f,0.f,0.f},{0.f,0.f,0.f,0.f}};
    f32x4 oacc[2][2];
#pragma unroll
    for (int x = 0; x < 2; x++) {
      oacc[x][0] = (f32x4){0.f, 0.f, 0.f, 0.f};
      oacc[x][1] = (f32x4){0.f, 0.f, 0.f, 0.f};
    }

    // ---- online softmax over 7 chunks of 32 j, two tiles interleaved ----
    for (int ck = 0; ck < 7; ck++) {
      // shared K fragments for both tiles — direct from global (L2 hit)
      short8 bfr[2];
#pragma unroll
      for (int t = 0; t < 2; t++) {
        int j = (ck * 2 + t) * 16 + c;
        int jc = j > 195 ? 195 : j;
        bfr[t] = *(const short8*)(Kg + (size_t)jc * 1152 + q * 8);
      }
      f32x4 s01[2][2];
#pragma unroll
      for (int x = 0; x < 2; x++) {
        f32x4 z = {0.f, 0.f, 0.f, 0.f};
        s01[x][0] = __builtin_amdgcn_mfma_f32_16x16x32_bf16(afrag[x], bfr[0], z, 0, 0, 0);
        s01[x][1] = __builtin_amdgcn_mfma_f32_16x16x32_bf16(afrag[x], bfr[1], z, 0, 0, 0);
      }
      // bucket LUT loads -> Rw gather (mask folded in via sentinel)
      uint8_t bk[2][2][4];
#pragma unroll
      for (int t = 0; t < 2; t++) {
        int jj = ck * 32 + t * 16 + c;
#pragma unroll
        for (int x = 0; x < 2; x++)
#pragma unroll
          for (int e = 0; e < 4; e++) bk[x][t][e] = lutG[lutOff[x][e] + jj];
      }
#pragma unroll
      for (int x = 0; x < 2; x++)
#pragma unroll
        for (int t = 0; t < 2; t++)
#pragma unroll
          for (int e = 0; e < 4; e++)
            s01[x][t][e] = s01[x][t][e] * SCALE2 + bf2f(Rw4[wv][x][rwOff[e] + bk[x][t][e]]);

      // per-tile shared chunk max + rescale + raw exp2 + P store (branch-free)
#pragma unroll
      for (int x = 0; x < 2; x++) {
        float mc = s01[x][0][0];
#pragma unroll
        for (int t = 0; t < 2; t++)
#pragma unroll
          for (int e = 0; e < 4; e++) mc = fmaxf(mc, s01[x][t][e]);
#pragma unroll
        for (int o = 1; o < 16; o <<= 1) mc = fmaxf(mc, __shfl_xor(mc, o, 64));
        float mn = fmaxf(mr[x], mc);
        float sc = __builtin_amdgcn_exp2f(mr[x] - mn);
        mr[x] = mn;
#pragma unroll
        for (int t = 0; t < 2; t++)
#pragma unroll
          for (int e = 0; e < 4; e++) s01[x][t][e] = __builtin_amdgcn_exp2f(s01[x][t][e] - mn);
#pragma unroll
        for (int e = 0; e < 4; e++) {
          l4[x][e] = l4[x][e] * sc + s01[x][0][e] + s01[x][1][e];
          oacc[x][0][e] *= sc; oacc[x][1][e] *= sc;
        }
#pragma unroll
        for (int t = 0; t < 2; t++) {
          int sl2 = t * 2 + (c >> 3);
#pragma unroll
          for (int e = 0; e < 4; e++) {
            union { float f; uint32_t u; } pv; pv.f = s01[x][t][e];
            Pc4[wv][x][(sl2 * 16 + q * 4 + e) * 8 + (c & 7)] = (u16)(pv.u >> 16);
          }
        }
      }
      // PV: shared V fragment, 2 MFMAs per tile
#pragma unroll
      for (int n2 = 0; n2 < 2; n2++) {
        short8 vb = *(const short8*)&Vt[(n2 * 16 + c) * 228 + ck * 32 + q * 8];
#pragma unroll
        for (int x = 0; x < 2; x++) {
          short8 pa = *(const short8*)&Pc4[wv][x][(q * 16 + c) * 8];
          oacc[x][n2] = __builtin_amdgcn_mfma_f32_16x16x32_bf16(pa, vb, oacc[x][n2], 0, 0, 0);
        }
      }
    }

    // ---- final 1/l and store per tile ----
#pragma unroll
    for (int x = 0; x < 2; x++) {
      if (x == 1 && !vB) continue;
      float inv[4];
#pragma unroll
      for (int e = 0; e < 4; e++) {
        float s2 = l4[x][e];
#pragma unroll
        for (int o = 1; o < 16; o <<= 1) s2 += __shfl_xor(s2, o, 64);
        inv[e] = 1.f / s2;
      }
#pragma unroll
      for (int n2 = 0; n2 < 2; n2++) {
#pragma unroll
        for (int e = 0; e < 4; e++) {
          int i = i0x[x] + e;
          if (i < 196) {
            int d = n2 * 16 + c;
            AO[((size_t)b * NPOS + i) * DM + h * 32 + d] = f2bf(oacc[x][n2][e] * inv[e]);
          }
        }
      }
    }
  }
}

// ---------------------------------------------------------------------------
// x (B, CIN, HW, HW) f32  ->  A_t (B*NPOS, CIN) bf16
// ---------------------------------------------------------------------------
__global__ __launch_bounds__(256) void transpose_cast_k(
    const float* __restrict__ x, u16* __restrict__ At)
{
  __shared__ float t[32][33];
  int c0 = blockIdx.x * 32, n0 = blockIdx.y * 32, b = blockIdx.z;
  int tx = threadIdx.x, ty = threadIdx.y;
  const float* xb = x + (size_t)b * CIN * NPOS;
#pragma unroll
  for (int i = 0; i < 4; i++) {
    int cc = c0 + ty + i * 8, nn = n0 + tx;
    t[ty + i * 8][tx] = (nn < NPOS) ? xb[(size_t)cc * NPOS + nn] : 0.f;
  }
  __syncthreads();
  u16* Ab = At + (size_t)b * NPOS * CIN;
#pragma unroll
  for (int i = 0; i < 4; i++) {
    int nn = n0 + ty + i * 8, cc = c0 + tx;
    if (nn < NPOS) Ab[(size_t)nn * CIN + cc] = f2bf(t[tx][ty + i * 8]);
  }
}

// ---------------------------------------------------------------------------
// depthwise 3x3 SAME conv + bias + identity residual (fp32)
// ---------------------------------------------------------------------------
__global__ __launch_bounds__(256) void conv_res_k(
    const float* __restrict__ T0, const float* __restrict__ pcw,
    const float* __restrict__ pcb, float* __restrict__ T1)
{
  int idx = blockIdx.x * 256 + threadIdx.x;
  if (idx >= B_ * NPOS * 96) return;
  int d4 = idx % 96; int rem = idx / 96;
  int n = rem % NPOS; int b = rem / NPOS;
  int hh = n / 14, ww = n % 14;
  int d0 = d4 * 4;
  float w9[4][9];
#pragma unroll
  for (int j = 0; j < 4; j++)
#pragma unroll
    for (int t = 0; t < 9; t++) w9[j][t] = pcw[(d0 + j) * 9 + t];
  const float* base = T0 + (size_t)b * NPOS * DM;
  float4 ctr = *(const float4*)(base + (size_t)n * DM + d0);
  float ax = ctr.x + pcb[d0], ay = ctr.y + pcb[d0 + 1];
  float az = ctr.z + pcb[d0 + 2], aw = ctr.w + pcb[d0 + 3];
#pragma unroll
  for (int kh = 0; kh < 3; kh++) {
    int h2 = hh + kh - 1;
    if (h2 < 0 || h2 >= 14) continue;
#pragma unroll
    for (int kw = 0; kw < 3; kw++) {
      int w2 = ww + kw - 1;
      if (w2 < 0 || w2 >= 14) continue;
      float4 v = *(const float4*)(base + (size_t)(h2 * 14 + w2) * DM + d0);
      int t = kh * 3 + kw;
      ax += v.x * w9[0][t]; ay += v.y * w9[1][t];
      az += v.z * w9[2][t]; aw += v.w * w9[3][t];
    }
  }
  float4 o = {ax, ay, az, aw};
  *(float4*)(T1 + (size_t)b * NPOS * DM + (size_t)n * DM + d0) = o;
}

// ---------------------------------------------------------------------------
// LayerNorm(384) f32 -> bf16, one wave per row (float2-vectorized)
// ---------------------------------------------------------------------------
__global__ __launch_bounds__(256) void ln_k(
    const float* __restrict__ in, const float* __restrict__ w,
    const float* __restrict__ bb, u16* __restrict__ out)
{
  int row = blockIdx.x * 4 + (threadIdx.x >> 6);
  int ln = threadIdx.x & 63;
  const float2* r = (const float2*)(in + (size_t)row * DM);
  float2 v[3]; float s = 0.f, sq = 0.f;
#pragma unroll
  for (int j = 0; j < 3; j++) {
    v[j] = r[ln + 64 * j];
    s += v[j].x + v[j].y; sq += v[j].x * v[j].x + v[j].y * v[j].y;
  }
#pragma unroll
  for (int o = 1; o < 64; o <<= 1) { s += __shfl_xor(s, o, 64); sq += __shfl_xor(sq, o, 64); }
  float mu = s * (1.f / 384.f);
  float var = sq * (1.f / 384.f) - mu * mu;
  float rs = rsqrtf(var + 1e-5f);
  uint32_t* orow = (uint32_t*)(out + (size_t)row * DM);
#pragma unroll
  for (int j = 0; j < 3; j++) {
    int d = (ln + 64 * j) * 2;
    float a = (v[j].x - mu) * rs * w[d] + bb[d];
    float bq = (v[j].y - mu) * rs * w[d + 1] + bb[d + 1];
    orow[ln + 64 * j] = (uint32_t)f2bf(a) | ((uint32_t)f2bf(bq) << 16);
  }
}

// ---------------------------------------------------------------------------
// BN1 over (batch, dmodel) per position n: two-stage stats
// ---------------------------------------------------------------------------
__global__ __launch_bounds__(256) void bn1_partial_k(
    const float* __restrict__ T3, float* __restrict__ part)
{
  int n = blockIdx.x >> 3, g = blockIdx.x & 7;
  int tid = threadIdx.x;
  float s = 0.f, sq = 0.f;
  for (int b2 = g * 16; b2 < g * 16 + 16; b2++) {
    const float* p = T3 + ((size_t)b2 * NPOS + n) * DM;
    for (int d = tid; d < DM; d += 256) { float v = p[d]; s += v; sq += v * v; }
  }
#pragma unroll
  for (int o = 1; o < 64; o <<= 1) { s += __shfl_xor(s, o, 64); sq += __shfl_xor(sq, o, 64); }
  __shared__ float ls[4], lq[4];
  int wv = tid >> 6, ln = tid & 63;
  if (ln == 0) { ls[wv] = s; lq[wv] = sq; }
  __syncthreads();
  if (tid == 0) {
    part[blockIdx.x * 2]     = ls[0] + ls[1] + ls[2] + ls[3];
    part[blockIdx.x * 2 + 1] = lq[0] + lq[1] + lq[2] + lq[3];
  }
}

__global__ __launch_bounds__(256) void bn1_finish_k(
    const float* __restrict__ part, const float* __restrict__ bw,
    const float* __restrict__ bbb, float* __restrict__ scaleArr,
    float* __restrict__ shiftArr)
{
  int n = threadIdx.x;
  if (n >= NPOS) return;
  float S = 0.f, Q = 0.f;
#pragma unroll
  for (int g = 0; g < 8; g++) { S += part[(n * 8 + g) * 2]; Q += part[(n * 8 + g) * 2 + 1]; }
  float mu = S / 49152.f;
  float var = Q / 49152.f - mu * mu;
  float rs = rsqrtf(var + 2e-5f);
  float sc = rs * bw[n];
  scaleArr[n] = sc;
  shiftArr[n] = bbb[n] - mu * sc;
}

__global__ __launch_bounds__(256) void bn1_apply_k(
    const float* __restrict__ T3, const float* __restrict__ scaleArr,
    const float* __restrict__ shiftArr, u16* __restrict__ outb)
{
  int idx = blockIdx.x * 256 + threadIdx.x;           // float4 index
  if (idx >= MT * DM / 4) return;
  int n = (idx / 96) % NPOS;
  float4 v = *(const float4*)(T3 + (size_t)idx * 4);
  float sc = scaleArr[n], sh = shiftArr[n];
  uint32_t p0 = (uint32_t)f2bf(v.x * sc + sh) | ((uint32_t)f2bf(v.y * sc + sh) << 16);
  uint32_t p1 = (uint32_t)f2bf(v.z * sc + sh) | ((uint32_t)f2bf(v.w * sc + sh) << 16);
  ((uint2*)outb)[idx] = make_uint2(p0, p1);
}

// ---------------------------------------------------------------------------
// split-K reduce for lin head + bias
// ---------------------------------------------------------------------------
__global__ __launch_bounds__(256) void lin_reduce_k(
    const float* __restrict__ part, const float* __restrict__ lb,
    float* __restrict__ y)
{
  int idx = blockIdx.x * 256 + threadIdx.x;
  if (idx >= 128 * DM) return;
  int col = idx % DM;
  float s = lb[col];
#pragma unroll
  for (int sp = 0; sp < 49; sp++) s += part[(size_t)sp * (128 * DM) + idx];
  y[idx] = s;
}

// ---------------------------------------------------------------------------
// BN2 over batch (128) per feature col, in-place on y
// ---------------------------------------------------------------------------
__global__ __launch_bounds__(64) void bn2_k(
    float* __restrict__ y, const float* __restrict__ w,
    const float* __restrict__ bb)
{
  int col = blockIdx.x; int ln = threadIdx.x;
  float v0 = y[(size_t)ln * DM + col];
  float v1 = y[(size_t)(ln + 64) * DM + col];
  float s = v0 + v1, sq = v0 * v0 + v1 * v1;
#pragma unroll
  for (int o = 1; o < 64; o <<= 1) { s += __shfl_xor(s, o, 64); sq += __shfl_xor(sq, o, 64); }
  float mu = s / 128.f;
  float var = sq / 128.f - mu * mu;
  float rs = rsqrtf(var + 2e-5f);
  float sc = rs * w[col], sh = bb[col] - mu * sc;
  y[(size_t)ln * DM + col] = v0 * sc + sh;
  y[(size_t)(ln + 64) * DM + col] = v1 * sc + sh;
}

// ---------------------------------------------------------------------------
// merged f32 -> bf16 cast for the six small weight matrices
// ---------------------------------------------------------------------------
__global__ __launch_bounds__(256) void castall_k(
    const float* __restrict__ s0, u16* __restrict__ d0,
    const float* __restrict__ s1, u16* __restrict__ d1,
    const float* __restrict__ s2, u16* __restrict__ d2,
    const float* __restrict__ s3, u16* __restrict__ d3,
    const float* __restrict__ s4, u16* __restrict__ d4,
    const float* __restrict__ s5, u16* __restrict__ d5)
{
  const int b0 = 262144, b1 = b0 + 98304, b2 = b1 + 110592,
            b3 = b2 + 36864, b4 = b3 + 147456, b5 = b4 + 147456; // 802816
  int idx = blockIdx.x * 256 + threadIdx.x;
  int stride = gridDim.x * 256;
  for (; idx < b5; idx += stride) {
    const float* s; u16* d; int l;
    if      (idx < b0) { s = s0; d = d0; l = idx; }
    else if (idx < b1) { s = s1; d = d1; l = idx - b0; }
    else if (idx < b2) { s = s2; d = d2; l = idx - b1; }
    else if (idx < b3) { s = s3; d = d3; l = idx - b2; }
    else if (idx < b4) { s = s4; d = d4; l = idx - b3; }
    else               { s = s5; d = d5; l = idx - b4; }
    float4 v = *(const float4*)(s + (size_t)l * 4);
    uint32_t p0 = (uint32_t)f2bf(v.x) | ((uint32_t)f2bf(v.y) << 16);
    uint32_t p1 = (uint32_t)f2bf(v.z) | ((uint32_t)f2bf(v.w) << 16);
    ((uint2*)d)[l] = make_uint2(p0, p1);
  }
}

// ---------------------------------------------------------------------------
// Orchestration
// ---------------------------------------------------------------------------
extern "C" void kernel_launch(void* const* d_in, const int* in_sizes, int n_in,
                              void* d_out, int out_size, void* d_ws, size_t ws_size,
                              hipStream_t stream)
{
  (void)in_sizes; (void)n_in; (void)out_size;
  const float* x    = (const float*)d_in[0];
  const float* fc1w = (const float*)d_in[1];
  const float* fc1b = (const float*)d_in[2];
  const float* fc2w = (const float*)d_in[3];
  const float* fc2b = (const float*)d_in[4];
  const float* pcw  = (const float*)d_in[5];
  const float* pcb  = (const float*)d_in[6];
  const float* ln1w = (const float*)d_in[7];
  const float* ln1b = (const float*)d_in[8];
  const float* qkvw = (const float*)d_in[9];
  const float* rpet = (const float*)d_in[10];
  const float* projw= (const float*)d_in[11];
  const float* projb= (const float*)d_in[12];
  const float* ln2w = (const float*)d_in[13];
  const float* ln2b = (const float*)d_in[14];
  const float* m1w  = (const float*)d_in[15];
  const float* m1b  = (const float*)d_in[16];
  const float* m2w  = (const float*)d_in[17];
  const float* m2b  = (const float*)d_in[18];
  const float* bn1w = (const float*)d_in[19];
  const float* bn1b = (const float*)d_in[20];
  const float* linw = (const float*)d_in[21];
  const float* linb = (const float*)d_in[22];
  const float* bn2w = (const float*)d_in[23];
  const float* bn2b = (const float*)d_in[24];
  float* y = (float*)d_out;

  // -------- aliased workspace layout (regions share by liveness) ----------
  const size_t RA = 0;                      // At / MLP1
  const size_t RB = 77070336;               // U / QKV / T3nb
  const size_t RC = RB + 57802752;          // H / AO / H2
  const size_t RD = RC + 19267584;          // T0 / T2
  const size_t RE = RD + 38535168;          // T1 / T3
  const size_t RF = RE + 38535168;          // PART (lin split-K)
  const size_t RG = RF + 9633792;           // small bf16 weights
  const size_t RS = RG + 6422528;           // bn1 scale/shift + partials + lut
  const size_t NEED = RS + 2048 + 16384 + 45056;
  if (ws_size < NEED) return;

  char* ws = (char*)d_ws;
  u16*   At    = (u16*)(ws + RA);
  u16*   MLP1  = (u16*)(ws + RA);
  u16*   U     = (u16*)(ws + RB);
  u16*   QKV   = (u16*)(ws + RB);
  u16*   T3nb  = (u16*)(ws + RB);
  u16*   H     = (u16*)(ws + RC);
  u16*   AO    = (u16*)(ws + RC);
  u16*   H2    = (u16*)(ws + RC);
  float* T0    = (float*)(ws + RD);
  float* T2    = (float*)(ws + RD);
  float* T1    = (float*)(ws + RE);
  float* T3    = (float*)(ws + RE);
  float* PART  = (float*)(ws + RF);
  u16*   wb_fc1 = (u16*)(ws + RG);
  u16*   wb_fc2 = wb_fc1 + 1048576;
  u16*   wb_qkv = wb_fc2 + 393216;
  u16*   wb_proj= wb_qkv + 442368;
  u16*   wb_m1  = wb_proj + 147456;
  u16*   wb_m2  = wb_m1 + 589824;
  float* bnS   = (float*)(ws + RS);
  float* bnSh  = bnS + 196;
  float* bnP   = (float*)(ws + RS + 2048);
  uint8_t* blut = (uint8_t*)(ws + RS + 2048 + 16384);

  // weight casts (f32 -> bf16), one merged kernel + bucket LUT
  castall_k<<<1024, 256, 0, stream>>>(fc1w, wb_fc1, fc2w, wb_fc2, qkvw, wb_qkv,
                                      projw, wb_proj, m1w, wb_m1, m2w, wb_m2);
  blut_k<<<196, 224, 0, stream>>>(blut);

  // x (B,CIN,N) -> At (B*N, CIN) bf16
  transpose_cast_k<<<dim3(32, 7, 128), dim3(32, 8), 0, stream>>>(x, At);

  // embed fc1: U = relu6(At @ fc1w^T + b)   [25088 x 1024]
  gemm_k<0><<<196 * 8, 256, 0, stream>>>(At, wb_fc1, fc1b, nullptr, U,
                                          MT, 1024, 1024, 1024, 1024, 8, 0);
  // embed fc2: T0 = U @ fc2w^T + b          [25088 x 384] f32
  gemm_k<1><<<196 * 3, 256, 0, stream>>>(U, wb_fc2, fc2b, nullptr, T0,
                                          MT, 384, 1024, 1024, 1024, 3, 0);
  // depthwise conv + bias + residual -> T1
  conv_res_k<<<(B_ * NPOS * 96 + 255) / 256, 256, 0, stream>>>(T0, pcw, pcb, T1);
  // LN1 -> H (bf16)
  ln_k<<<MT / 4, 256, 0, stream>>>(T1, ln1w, ln1b, H);
  // qkv: QKV = H @ qkvw^T (no bias)          [25088 x 1152] bf16
  gemm_k<2><<<196 * 9, 256, 0, stream>>>(H, wb_qkv, nullptr, nullptr, QKV,
                                          MT, 1152, 384, 384, 384, 9, 0);
  // fused attention (rpe in-kernel, flash-style, LUT bias, 2-tile ILP,
  // K direct from L2, 4 blocks/CU) -> AO
  attn_k<<<1536, 256, 0, stream>>>(QKV, rpet, blut, AO);
  // proj + residual(T1) -> T2 (f32)
  gemm_k<3><<<196 * 3, 256, 0, stream>>>(AO, wb_proj, projb, T1, T2,
                                          MT, 384, 384, 384, 384, 3, 0);
  // LN2 -> H2 (bf16)
  ln_k<<<MT / 4, 256, 0, stream>>>(T2, ln2w, ln2b, H2);
  // mlp fc1: MLP1 = relu6(H2 @ m1w^T + b)    [25088 x 1536] bf16
  gemm_k<0><<<196 * 12, 256, 0, stream>>>(H2, wb_m1, m1b, nullptr, MLP1,
                                           MT, 1536, 384, 384, 384, 12, 0);
  // mlp fc2 + residual(T2) -> T3 (f32)
  gemm_k<3><<<196 * 3, 256, 0, stream>>>(MLP1, wb_m2, m2b, T2, T3,
                                          MT, 384, 1536, 1536, 1536, 3, 0);
  // BN1 (per position) -> T3nb (bf16)
  bn1_partial_k<<<196 * 8, 256, 0, stream>>>(T3, bnP);
  bn1_finish_k<<<1, 256, 0, stream>>>(bnP, bn1w, bn1b, bnS, bnSh);
  bn1_apply_k<<<(MT * DM / 4 + 255) / 256, 256, 0, stream>>>(T3, bnS, bnSh, T3nb);
  // lin head: y = T3nb(128 x 75264) @ linw^T, split-K 49 x 1536 (W f32 direct)
  gemm_k<4><<<3 * 49, 256, 0, stream>>>(T3nb, linw, nullptr, nullptr, PART,
                                         128, 384, 1536, 75264, 75264, 3, 1536);
  lin_reduce_k<<<192, 256, 0, stream>>>(PART, linb, y);
  // BN2 (per feature over batch), in place on d_out
  bn2_k<<<384, 64, 0, stream>>>(y, bn2w, bn2b);
}

// Round 24
// 537.569 us; speedup vs baseline: 1.0655x; 1.0157x over previous
//
#include <hip/hip_runtime.h>
#include <cstdint>

// ---------------------------------------------------------------------------
// Problem constants
// ---------------------------------------------------------------------------
#define B_    128
#define CIN   1024
#define NPOS  196          // 14*14
#define DM    384
#define NH_   12
#define HD_   32
#define DFF_  1536
#define MT    25088        // B_*NPOS
#define SCALE_Q 0.17677669529663687f   // 1/sqrt(32)
#define SCALE2  0.25503485810335155f   // SCALE_Q * log2(e)  (exp2 domain)

typedef unsigned short u16;
typedef __attribute__((ext_vector_type(8))) short  short8;   // 8 bf16 (4 VGPR)
typedef __attribute__((ext_vector_type(4))) float  f32x4;    // MFMA C/D

__device__ __forceinline__ u16 f2bf(float f) {
  union { float f; uint32_t u; } v; v.f = f;
  uint32_t u = v.u;
  return (u16)((u + 0x7fffu + ((u >> 16) & 1u)) >> 16);
}
__device__ __forceinline__ float bf2f(u16 h) {
  union { uint32_t u; float f; } v; v.u = ((uint32_t)h) << 16;
  return v.f;
}

#define GLDS16(g, l)                                                           \
  __builtin_amdgcn_global_load_lds(                                            \
      (const __attribute__((address_space(1))) void*)(g),                      \
      (__attribute__((address_space(3))) void*)(l), 16, 0, 0)

// ---------------------------------------------------------------------------
// r24: 256x256 8-phase GEMM (HK-style schedule in plain HIP) for shapes with
// M%256==0, N%256==0, K%128==0 (fc1: 25088x1024x1024, mlp1: 25088x1536x384).
// 512 thr / 8 waves (2M x 4N); per-wave C = 128x64 (acc[8][4]).
// LDS 128KB: As/Bs[2 dbuf][2 half][ [2 ks][128 r][32 k] ] bf16, st_16x32
// swizzle (k-group ^= 2 when row bit3 set) via PRE-SWIZZLED global source +
// linear GLDS dest; reads apply the same XOR.
// Schedule per K-tile t (4 phases): ph1 {8 B-frag + 4 A-frag ds_reads, stage
// A0(t+1)}, ph2 {4 A-reads, stage A1(t+1)}, ph3 {4 A-reads, stage B0(t+2)},
// ph4 {4 A-reads, stage B1(t+2), vmcnt(4)}. Each phase: barrier; lgkmcnt(0);
// setprio(1); 16 MFMA; setprio(0); barrier. Per-wave vmcnt BEFORE the
// tile-end barrier => barrier certifies all waves' tile-(t+1) stages landed.
// Every stage target is >=2 barriers past its last reader (A(t+1): dead since
// end of t-1; B(t+2): dead after t ph1's lgkmcnt+barrier).
// Epilogue: bias + relu6 -> bf16 (both users are MODE-0 shaped).
// ---------------------------------------------------------------------------
template<int M0>
__device__ __forceinline__ void phase_mfma(f32x4 (&acc)[8][4],
                                           short8 (&a_)[2][2],
                                           short8 (&b_)[4][2]) {
#pragma unroll
  for (int m2 = 0; m2 < 2; m2++)
#pragma unroll
    for (int n = 0; n < 4; n++)
#pragma unroll
      for (int ks = 0; ks < 2; ks++)
        acc[M0 + m2][n] = __builtin_amdgcn_mfma_f32_16x16x32_bf16(
            a_[m2][ks], b_[n][ks], acc[M0 + m2][n], 0, 0, 0);
}

__global__ __launch_bounds__(512) void gemm256_k(
    const u16* __restrict__ A, const u16* __restrict__ W,
    const float* __restrict__ bias, u16* __restrict__ out,
    int M, int N, int K, int lda, int ldw, int nTN)
{
  __shared__ __align__(16) u16 As[2][2][8192];   // [dbuf][half][ks*4096+r*32+kg*8]
  __shared__ __align__(16) u16 Bs[2][2][8192];

  int nwg = gridDim.x, bid0 = blockIdx.x;
  int qq = nwg >> 3, rr = nwg & 7;
  int xcd = bid0 & 7, idx = bid0 >> 3;
  int bid = (xcd < rr ? xcd * (qq + 1) : rr * (qq + 1) + (xcd - rr) * qq) + idx;

  int mT = bid / nTN, nT = bid % nTN;
  int mBase = mT * 256, nBase = nT * 256;

  int tid = threadIdx.x;
  int w = tid >> 6, ln = tid & 63;
  int q = ln >> 4, cc = ln & 15;
  int wr = w >> 2, wc = w & 3;          // 2 x 4 wave grid

  const u16* Ag = A + (size_t)mBase * lda;
  const u16* Wg = W + (size_t)nBase * ldw;

  int srow = ln >> 2;                   // staging: row-within-16
  int skg  = ln & 3;                    // staging: k-group slot

  f32x4 acc[8][4];
#pragma unroll
  for (int i = 0; i < 8; i++)
#pragma unroll
    for (int j = 0; j < 4; j++) acc[i][j] = (f32x4){0.f, 0.f, 0.f, 0.f};

  int NT = K >> 6;                      // 64-wide K-tiles (even, >=2)

  auto STAGE_A = [&](int t, int half) {
#pragma unroll
    for (int i = 0; i < 2; i++) {
      int c8 = w * 2 + i;               // chunk 0..15 (1KB each)
      int h2 = c8 >> 3;
      int row = ((c8 & 7) << 4) + srow;
      int kg = skg ^ (((row >> 3) & 1) << 1);      // pre-swizzled source
      GLDS16(Ag + (size_t)(half * 128 + row) * lda + t * 64 + h2 * 32 + kg * 8,
             &As[t & 1][half][c8 << 9]);
    }
  };
  auto STAGE_B = [&](int t, int half) {
#pragma unroll
    for (int i = 0; i < 2; i++) {
      int c8 = w * 2 + i;
      int h2 = c8 >> 3;
      int row = ((c8 & 7) << 4) + srow;
      int kg = skg ^ (((row >> 3) & 1) << 1);
      GLDS16(Wg + (size_t)(half * 128 + row) * ldw + t * 64 + h2 * 32 + kg * 8,
             &Bs[t & 1][half][c8 << 9]);
    }
  };

  // ---- prologue: tiles 0 and 1 fully staged ----
  STAGE_A(0, 0); STAGE_A(0, 1); STAGE_B(0, 0); STAGE_B(0, 1);
  if (NT > 1) {
    STAGE_A(1, 0); STAGE_A(1, 1); STAGE_B(1, 0); STAGE_B(1, 1);
    asm volatile("s_waitcnt vmcnt(8)" ::: "memory");   // tile 0 landed
  } else {
    asm volatile("s_waitcnt vmcnt(0)" ::: "memory");
  }
  __builtin_amdgcn_s_barrier();

  for (int t = 0; t < NT; ++t) {
    int d = t & 1;
    short8 b_[4][2], a_[2][2];

    auto LOAD_A = [&](int m0) {
      int fr0 = m0 * 16 + cc;
      int sw0 = ((fr0 >> 3) & 1) << 1;
      a_[0][0] = *(const short8*)&As[d][wr][fr0 * 32 + ((q ^ sw0) << 3)];
      a_[0][1] = *(const short8*)&As[d][wr][4096 + fr0 * 32 + ((q ^ sw0) << 3)];
      int fr1 = fr0 + 16;
      int sw1 = ((fr1 >> 3) & 1) << 1;
      a_[1][0] = *(const short8*)&As[d][wr][fr1 * 32 + ((q ^ sw1) << 3)];
      a_[1][1] = *(const short8*)&As[d][wr][4096 + fr1 * 32 + ((q ^ sw1) << 3)];
    };

    // -------- phase 1: all B frags + A frags 0,1; stage A0(t+1) --------
#pragma unroll
    for (int n = 0; n < 4; n++) {
      int fcl = (wc & 1) * 64 + n * 16 + cc;
      int sw = ((fcl >> 3) & 1) << 1;
      b_[n][0] = *(const short8*)&Bs[d][wc >> 1][fcl * 32 + ((q ^ sw) << 3)];
      b_[n][1] = *(const short8*)&Bs[d][wc >> 1][4096 + fcl * 32 + ((q ^ sw) << 3)];
    }
    LOAD_A(0);
    if (t >= 1 && t + 1 < NT) STAGE_A(t + 1, 0);
    __builtin_amdgcn_s_barrier();
    asm volatile("s_waitcnt lgkmcnt(0)" ::: "memory");
    __builtin_amdgcn_sched_barrier(0);
    __builtin_amdgcn_s_setprio(1);
    phase_mfma<0>(acc, a_, b_);
    __builtin_amdgcn_s_setprio(0);
    __builtin_amdgcn_s_barrier();

    // -------- phase 2: A frags 2,3; stage A1(t+1) --------
    LOAD_A(2);
    if (t >= 1 && t + 1 < NT) STAGE_A(t + 1, 1);
    __builtin_amdgcn_s_barrier();
    asm volatile("s_waitcnt lgkmcnt(0)" ::: "memory");
    __builtin_amdgcn_sched_barrier(0);
    __builtin_amdgcn_s_setprio(1);
    phase_mfma<2>(acc, a_, b_);
    __builtin_amdgcn_s_setprio(0);
    __builtin_amdgcn_s_barrier();

    // -------- phase 3: A frags 4,5; stage B0(t+2) --------
    LOAD_A(4);
    if (t + 2 < NT) STAGE_B(t + 2, 0);
    __builtin_amdgcn_s_barrier();
    asm volatile("s_waitcnt lgkmcnt(0)" ::: "memory");
    __builtin_amdgcn_sched_barrier(0);
    __builtin_amdgcn_s_setprio(1);
    phase_mfma<4>(acc, a_, b_);
    __builtin_amdgcn_s_setprio(0);
    __builtin_amdgcn_s_barrier();

    // -------- phase 4: A frags 6,7; stage B1(t+2); tile gate --------
    LOAD_A(6);
    if (t + 2 < NT) STAGE_B(t + 2, 1);
    __builtin_amdgcn_s_barrier();
    asm volatile("s_waitcnt lgkmcnt(0)" ::: "memory");
    __builtin_amdgcn_sched_barrier(0);
    __builtin_amdgcn_s_setprio(1);
    phase_mfma<6>(acc, a_, b_);
    __builtin_amdgcn_s_setprio(0);
    if (t + 1 < NT) {
      if (t + 2 < NT)
        asm volatile("s_waitcnt vmcnt(4)" ::: "memory");  // only B(t+2) pending
      else
        asm volatile("s_waitcnt vmcnt(0)" ::: "memory");
    }
    __builtin_amdgcn_s_barrier();      // certifies tile t+1 landed (all waves)
  }

  // ---- epilogue: bias + relu6 -> bf16 ----
#pragma unroll
  for (int m = 0; m < 8; m++) {
    int row0 = mBase + wr * 128 + m * 16 + q * 4;
#pragma unroll
    for (int n = 0; n < 4; n++) {
      int col = nBase + wc * 64 + n * 16 + cc;
      float bv = bias[col];
      f32x4 v = acc[m][n];
#pragma unroll
      for (int e = 0; e < 4; e++) {
        float x = fminf(fmaxf(v[e] + bv, 0.f), 6.f);
        out[(size_t)(row0 + e) * N + col] = f2bf(x);
      }
    }
  }
}

// ---------------------------------------------------------------------------
// Generic bf16 MFMA GEMM (r20 best: triple-buffer, 1 barrier/K-step; GLDS
// with pre-swizzled source; counted vmcnt; XCD-chunked bijective swizzle).
// MODE: 0 = bias+relu6 -> bf16 | 1 = bias -> f32 | 2 = plain -> bf16
//       3 = bias+res -> f32    | 4 = split-K partial -> f32
// ---------------------------------------------------------------------------
template <int MODE>
__global__ __launch_bounds__(256) void gemm_k(
    const u16* __restrict__ A, const void* __restrict__ Wv,
    const float* __restrict__ bias, const float* __restrict__ res,
    void* __restrict__ outp,
    int M, int N, int K, int lda, int ldw, int nTN, int splitK)
{
  __shared__ __align__(16) u16 As[3][128 * 32];   // row-major [r][kphys]
  __shared__ __align__(16) u16 Bs[3][128 * 32];

  int nwg = gridDim.x;
  int bid0 = blockIdx.x;
  int qq = nwg >> 3, rr = nwg & 7;
  int xcd = bid0 & 7, idx = bid0 >> 3;
  int bid = (xcd < rr ? xcd * (qq + 1) : rr * (qq + 1) + (xcd - rr) * qq) + idx;

  int split = 0, mT, nT;
  if (MODE == 4) { split = bid / nTN; nT = bid % nTN; mT = 0; }
  else           { mT = bid / nTN;    nT = bid % nTN; }

  const u16* Ab = A + (size_t)split * splitK;
  float* outF = (float*)outp + ((MODE == 4) ? (size_t)split * (size_t)M * N : (size_t)0);
  u16*   outU = (u16*)outp;

  int tid = threadIdx.x;
  int wv = tid >> 6, ln = tid & 63;
  int q = ln >> 4, c = ln & 15;
  int wr = wv >> 1, wc = wv & 1;
  int mBase = mT * 128, nBase = nT * 128;

  f32x4 acc[4][4];
#pragma unroll
  for (int i = 0; i < 4; i++)
#pragma unroll
    for (int j = 0; j < 4; j++) acc[i][j] = (f32x4){0.f, 0.f, 0.f, 0.f};

  const u16* Ag = Ab + (size_t)mBase * lda;
  const u16*  Wg16 = (const u16*)Wv + (size_t)split * splitK + (size_t)nBase * ldw;
  const float* Wg32 = (const float*)Wv + (size_t)split * splitK + (size_t)nBase * ldw;

  int sl = ln & 3, rsub = ln >> 2;          // lane -> (phys kslot, row-in-16)
  int lk = sl ^ ((rsub >> 1) & 3);          // logical kslot this lane fetches

  float4 rbf[2][2];                         // MODE 4: raw f32 W held in regs

  auto STAGE = [&](int t, int buf) {
    int k0 = t * 32;
#pragma unroll
    for (int i = 0; i < 2; i++) {
      int rb = wv * 32 + i * 16;            // wave-uniform row base
      GLDS16(Ag + (size_t)(rb + rsub) * lda + k0 + lk * 8, &As[buf][rb * 32]);
      if constexpr (MODE != 4)
        GLDS16(Wg16 + (size_t)(rb + rsub) * ldw + k0 + lk * 8, &Bs[buf][rb * 32]);
    }
  };
  auto LOADW = [&](int t) {                 // MODE 4: coalesced f32 W load
    int k0 = t * 32;
#pragma unroll
    for (int i = 0; i < 2; i++) {
      const float* wp = Wg32 + (size_t)(wv * 32 + i * 16 + rsub) * ldw + k0 + sl * 8;
      rbf[i][0] = *(const float4*)wp;
      rbf[i][1] = *(const float4*)(wp + 4);
    }
  };
  auto WRITEW = [&](int buf) {              // MODE 4: write to swz layout
#pragma unroll
    for (int i = 0; i < 2; i++) {
      int rloc = wv * 32 + i * 16 + rsub;
      short8 pk;
      pk[0] = (short)f2bf(rbf[i][0].x); pk[1] = (short)f2bf(rbf[i][0].y);
      pk[2] = (short)f2bf(rbf[i][0].z); pk[3] = (short)f2bf(rbf[i][0].w);
      pk[4] = (short)f2bf(rbf[i][1].x); pk[5] = (short)f2bf(rbf[i][1].y);
      pk[6] = (short)f2bf(rbf[i][1].z); pk[7] = (short)f2bf(rbf[i][1].w);
      *(short8*)&Bs[buf][rloc * 32 + (sl ^ ((rsub >> 1) & 3)) * 8] = pk;
    }
  };

  int NT = K >> 5;   // K-steps of 32 (all K are multiples of 32)
  int ksw = (c >> 1) & 3;   // read-side kslot swizzle for this lane's rows

  if constexpr (MODE == 4) {
    // ---- 2-buffer drain schedule (lin head, small share of runtime) ----
    STAGE(0, 0);
    LOADW(0);
    WRITEW(0);
    asm volatile("s_waitcnt vmcnt(0) lgkmcnt(0)" ::: "memory");
    __builtin_amdgcn_s_barrier();
    int cur = 0;
    for (int t = 0; t < NT; ++t) {
      short8 afr[4], bfr[4];
#pragma unroll
      for (int mt2 = 0; mt2 < 4; mt2++)
        afr[mt2] = *(const short8*)&As[cur][(wr * 64 + mt2 * 16 + c) * 32 + (q ^ ksw) * 8];
#pragma unroll
      for (int nt2 = 0; nt2 < 4; nt2++)
        bfr[nt2] = *(const short8*)&Bs[cur][(wc * 64 + nt2 * 16 + c) * 32 + (q ^ ksw) * 8];
      asm volatile("s_waitcnt lgkmcnt(0)" ::: "memory");
      __builtin_amdgcn_sched_barrier(0);
      __builtin_amdgcn_s_barrier();
      if (t + 1 < NT) { STAGE(t + 1, cur ^ 1); LOADW(t + 1); WRITEW(cur ^ 1); }
      __builtin_amdgcn_sched_barrier(0);
#pragma unroll
      for (int mt2 = 0; mt2 < 4; mt2++)
#pragma unroll
        for (int nt2 = 0; nt2 < 4; nt2++)
          acc[mt2][nt2] = __builtin_amdgcn_mfma_f32_16x16x32_bf16(
              afr[mt2], bfr[nt2], acc[mt2][nt2], 0, 0, 0);
      if (t + 1 < NT) {
        asm volatile("s_waitcnt vmcnt(0) lgkmcnt(0)" ::: "memory");
        __builtin_amdgcn_s_barrier();
        cur ^= 1;
      }
    }
  } else {
    // ---- triple-buffer, 1 barrier per K-step ----
    STAGE(0, 0);
    if (NT > 1) {
      STAGE(1, 1);
      asm volatile("s_waitcnt vmcnt(4)" ::: "memory");   // tile 0 complete
    } else {
      asm volatile("s_waitcnt vmcnt(0)" ::: "memory");
    }
    __builtin_amdgcn_s_barrier();

    int cb = 0, sb = 2;   // current buf = t%3, stage buf = (t+2)%3
    for (int t = 0; t < NT; ++t) {
      short8 afr[4], bfr[4];
#pragma unroll
      for (int mt2 = 0; mt2 < 4; mt2++)
        afr[mt2] = *(const short8*)&As[cb][(wr * 64 + mt2 * 16 + c) * 32 + (q ^ ksw) * 8];
#pragma unroll
      for (int nt2 = 0; nt2 < 4; nt2++)
        bfr[nt2] = *(const short8*)&Bs[cb][(wc * 64 + nt2 * 16 + c) * 32 + (q ^ ksw) * 8];
      if (t + 2 < NT) STAGE(t + 2, sb);    // different buffer than any reader
      __builtin_amdgcn_sched_barrier(0);
#pragma unroll
      for (int mt2 = 0; mt2 < 4; mt2++)
#pragma unroll
        for (int nt2 = 0; nt2 < 4; nt2++)
          acc[mt2][nt2] = __builtin_amdgcn_mfma_f32_16x16x32_bf16(
              afr[mt2], bfr[nt2], acc[mt2][nt2], 0, 0, 0);
      if (t + 1 < NT) {
        if (t + 2 < NT)
          asm volatile("s_waitcnt vmcnt(4)" ::: "memory");  // t+1 done; t+2 in flight
        else
          asm volatile("s_waitcnt vmcnt(0)" ::: "memory");
        __builtin_amdgcn_s_barrier();                       // the ONLY barrier
      }
      cb = (cb == 2) ? 0 : cb + 1;
      sb = (sb == 2) ? 0 : sb + 1;
    }
  }

  // ---- epilogue ----
#pragma unroll
  for (int mt2 = 0; mt2 < 4; mt2++) {
    int row0 = mBase + wr * 64 + mt2 * 16 + q * 4;
#pragma unroll
    for (int nt2 = 0; nt2 < 4; nt2++) {
      int col = nBase + wc * 64 + nt2 * 16 + c;
      float bv = (MODE == 0 || MODE == 1 || MODE == 3) ? bias[col] : 0.f;
      f32x4 v = acc[mt2][nt2];
#pragma unroll
      for (int e = 0; e < 4; e++) {
        int row = row0 + e;
        float x = v[e] + bv;
        if (MODE == 0) x = fminf(fmaxf(x, 0.f), 6.f);
        if (MODE == 3) x += res[(size_t)row * N + col];
        if (MODE == 0 || MODE == 2) outU[(size_t)row * N + col] = f2bf(x);
        else                        outF[(size_t)row * N + col] = x;
      }
    }
  }
}

// ---------------------------------------------------------------------------
// Bucket LUT: lut[i][j] (u8, stride 224) = rp bucket 0..48 for j<196, 49
// (sentinel -> Rw[..][49] = -inf) for j in [196,224). Same for all (b,h).
// ---------------------------------------------------------------------------
__global__ __launch_bounds__(224) void blut_k(uint8_t* __restrict__ lut)
{
  int i = blockIdx.x;          // 0..195
  int j = threadIdx.x;         // 0..223
  uint8_t v = 49;
  if (j < 196) {
    int ri = i / 14, ci = i - ri * 14;
    int rj = j / 14, cj = j - rj * 14;
    int dr = ri - rj, dc = ci - cj;
    int adr = dr < 0 ? -dr : dr, adc = dc < 0 ? -dc : dc;
    int tr = adr <= 1 ? adr : (adr <= 3 ? 2 : 3);
    int tc = adc <= 1 ? adc : (adc <= 3 ? 2 : 3);
    int fr = dr < 0 ? -tr : tr, fc = dc < 0 ? -tc : tc;
    v = (uint8_t)(fr * 7 + fc + 24);
  }
  lut[i * 224 + j] = v;
}

// ---------------------------------------------------------------------------
// Fused attention per (b,h), flash-style over 7 j-chunks of 32, 2-tile ILP.
// (r23 best: K direct from L2, 4 blocks/CU; raw exp2 domain)
// LDS = 14592(Vt) + 8192(Pc) + 3136(Ts) + 12800(Rw) = 38720 B.
// ---------------------------------------------------------------------------
__global__ __launch_bounds__(256) void attn_k(
    const u16* __restrict__ QKV, const float* __restrict__ tabG,
    const uint8_t* __restrict__ lutG, u16* __restrict__ AO)
{
  __shared__ __align__(16) u16 Vt[32 * 228];         // [d][j], pad j>=196 zero
  __shared__ __align__(16) u16 Pc4[4][2][512];       // per-wave, per-tile P chunk
  __shared__ __align__(16) u16 Ts[49 * 32];          // rpe table, [t][k] bf16
  __shared__ __align__(16) u16 Rw4[4][2][16 * 50];   // per-wave, per-tile rpe
  int bh = blockIdx.x; int b = bh / NH_, h = bh % NH_;
  int tid = threadIdx.x;
  int wv = tid >> 6, ln = tid & 63;
  int q = ln >> 4, c = ln & 15;
  size_t rowbase = (size_t)b * NPOS * 1152 + h * 32;
  const u16* Kg = QKV + rowbase + 384;     // K base for this (b,h)

  // ---- stage rpe table transposed to [t][k] bf16 (once per block) ----
  for (int t = tid; t < 49 * 32; t += 256) {
    int tt = t >> 5, k = t & 31;
    Ts[t] = f2bf(tabG[k * 49 + tt]);
  }
  // ---- stage V transposed (vectorized) ----
  for (int t = tid; t < 784; t += 256) {
    int nn = t >> 2, d0 = (t & 3) * 8;
    short8 v = *(const short8*)(QKV + rowbase + 768 + (size_t)nn * 1152 + d0);
#pragma unroll
    for (int j = 0; j < 8; j++) Vt[(d0 + j) * 228 + nn] = (u16)v[j];
  }
  for (int t = tid; t < 32 * 32; t += 256) {
    int d = t >> 5, jj = 196 + (t & 31);
    Vt[d * 228 + jj] = 0;
  }
  __syncthreads();

  for (int it = 0; it < 2; ++it) {
    int mtA = wv + it * 8;                 // always < 13 (wv<=3 -> <=11)
    bool vB = (mtA + 4) < 13;
    int mbx[2];
    mbx[0] = mtA * 16;
    mbx[1] = (vB ? (mtA + 4) : 12) * 16;   // clamp; discarded if !vB

    short8 afrag[2];
    int i0x[2], lutOff[2][4];
#pragma unroll
    for (int x = 0; x < 2; x++) {
      int irow = mbx[x] + c; if (irow > 195) irow = 195;
      afrag[x] = *(const short8*)(QKV + rowbase + (size_t)irow * 1152 + q * 8);
      i0x[x] = mbx[x] + q * 4;
#pragma unroll
      for (int e = 0; e < 4; e++) {
        int i = i0x[x] + e; if (i > 195) i = 195;
        lutOff[x][e] = i * 224;
      }
    }
    int rwOff[4];
#pragma unroll
    for (int e = 0; e < 4; e++) rwOff[e] = (q * 4 + e) * 50;

    // ---- rpe scores via MFMA -> Rw, exp2 domain (SCALE2) ----
#pragma unroll
    for (int nt = 0; nt < 4; nt++) {
      int t = nt * 16 + c;
      int tt = t < 49 ? t : 48;
      short8 tb = *(const short8*)&Ts[tt * 32 + q * 8];
#pragma unroll
      for (int x = 0; x < 2; x++) {
        f32x4 z = {0.f, 0.f, 0.f, 0.f};
        f32x4 rr = __builtin_amdgcn_mfma_f32_16x16x32_bf16(afrag[x], tb, z, 0, 0, 0);
        if (t < 49) {
#pragma unroll
          for (int e = 0; e < 4; e++)
            Rw4[wv][x][rwOff[e] + t] = f2bf(rr[e] * SCALE2);
        }
      }
    }
    if (c == 0) {
#pragma unroll
      for (int x = 0; x < 2; x++)
#pragma unroll
        for (int e = 0; e < 4; e++)
          Rw4[wv][x][rwOff[e] + 49] = 0xFF80;   // bf16 -inf
    }

    float mr[2] = {-INFINITY, -INFINITY};
    float l4[2][4] = {{0.f,0.f,0.f,0.f},{0.f,0.f,0.f,0.f}};
    f32x4 oacc[2][2];
#pragma unroll
    for (int x = 0; x < 2; x++) {
      oacc[x][0] = (f32x4){0.f, 0.f, 0.f, 0.f};
      oacc[x][1] = (f32x4){0.f, 0.f, 0.f, 0.f};
    }

    // ---- online softmax over 7 chunks of 32 j, two tiles interleaved ----
    for (int ck = 0; ck < 7; ck++) {
      // shared K fragments for both tiles — direct from global (L2 hit)
      short8 bfr[2];
#pragma unroll
      for (int t = 0; t < 2; t++) {
        int j = (ck * 2 + t) * 16 + c;
        int jc = j > 195 ? 195 : j;
        bfr[t] = *(const short8*)(Kg + (size_t)jc * 1152 + q * 8);
      }
      f32x4 s01[2][2];
#pragma unroll
      for (int x = 0; x < 2; x++) {
        f32x4 z = {0.f, 0.f, 0.f, 0.f};
        s01[x][0] = __builtin_amdgcn_mfma_f32_16x16x32_bf16(afrag[x], bfr[0], z, 0, 0, 0);
        s01[x][1] = __builtin_amdgcn_mfma_f32_16x16x32_bf16(afrag[x], bfr[1], z, 0, 0, 0);
      }
      // bucket LUT loads -> Rw gather (mask folded in via sentinel)
      uint8_t bk[2][2][4];
#pragma unroll
      for (int t = 0; t < 2; t++) {
        int jj = ck * 32 + t * 16 + c;
#pragma unroll
        for (int x = 0; x < 2; x++)
#pragma unroll
          for (int e = 0; e < 4; e++) bk[x][t][e] = lutG[lutOff[x][e] + jj];
      }
#pragma unroll
      for (int x = 0; x < 2; x++)
#pragma unroll
        for (int t = 0; t < 2; t++)
#pragma unroll
          for (int e = 0; e < 4; e++)
            s01[x][t][e] = s01[x][t][e] * SCALE2 + bf2f(Rw4[wv][x][rwOff[e] + bk[x][t][e]]);

      // per-tile shared chunk max + rescale + raw exp2 + P store (branch-free)
#pragma unroll
      for (int x = 0; x < 2; x++) {
        float mc = s01[x][0][0];
#pragma unroll
        for (int t = 0; t < 2; t++)
#pragma unroll
          for (int e = 0; e < 4; e++) mc = fmaxf(mc, s01[x][t][e]);
#pragma unroll
        for (int o = 1; o < 16; o <<= 1) mc = fmaxf(mc, __shfl_xor(mc, o, 64));
        float mn = fmaxf(mr[x], mc);
        float sc = __builtin_amdgcn_exp2f(mr[x] - mn);
        mr[x] = mn;
#pragma unroll
        for (int t = 0; t < 2; t++)
#pragma unroll
          for (int e = 0; e < 4; e++) s01[x][t][e] = __builtin_amdgcn_exp2f(s01[x][t][e] - mn);
#pragma unroll
        for (int e = 0; e < 4; e++) {
          l4[x][e] = l4[x][e] * sc + s01[x][0][e] + s01[x][1][e];
          oacc[x][0][e] *= sc; oacc[x][1][e] *= sc;
        }
#pragma unroll
        for (int t = 0; t < 2; t++) {
          int sl2 = t * 2 + (c >> 3);
#pragma unroll
          for (int e = 0; e < 4; e++) {
            union { float f; uint32_t u; } pv; pv.f = s01[x][t][e];
            Pc4[wv][x][(sl2 * 16 + q * 4 + e) * 8 + (c & 7)] = (u16)(pv.u >> 16);
          }
        }
      }
      // PV: shared V fragment, 2 MFMAs per tile
#pragma unroll
      for (int n2 = 0; n2 < 2; n2++) {
        short8 vb = *(const short8*)&Vt[(n2 * 16 + c) * 228 + ck * 32 + q * 8];
#pragma unroll
        for (int x = 0; x < 2; x++) {
          short8 pa = *(const short8*)&Pc4[wv][x][(q * 16 + c) * 8];
          oacc[x][n2] = __builtin_amdgcn_mfma_f32_16x16x32_bf16(pa, vb, oacc[x][n2], 0, 0, 0);
        }
      }
    }

    // ---- final 1/l and store per tile ----
#pragma unroll
    for (int x = 0; x < 2; x++) {
      if (x == 1 && !vB) continue;
      float inv[4];
#pragma unroll
      for (int e = 0; e < 4; e++) {
        float s2 = l4[x][e];
#pragma unroll
        for (int o = 1; o < 16; o <<= 1) s2 += __shfl_xor(s2, o, 64);
        inv[e] = 1.f / s2;
      }
#pragma unroll
      for (int n2 = 0; n2 < 2; n2++) {
#pragma unroll
        for (int e = 0; e < 4; e++) {
          int i = i0x[x] + e;
          if (i < 196) {
            int d = n2 * 16 + c;
            AO[((size_t)b * NPOS + i) * DM + h * 32 + d] = f2bf(oacc[x][n2][e] * inv[e]);
          }
        }
      }
    }
  }
}

// ---------------------------------------------------------------------------
// x (B, CIN, HW, HW) f32  ->  A_t (B*NPOS, CIN) bf16
// ---------------------------------------------------------------------------
__global__ __launch_bounds__(256) void transpose_cast_k(
    const float* __restrict__ x, u16* __restrict__ At)
{
  __shared__ float t[32][33];
  int c0 = blockIdx.x * 32, n0 = blockIdx.y * 32, b = blockIdx.z;
  int tx = threadIdx.x, ty = threadIdx.y;
  const float* xb = x + (size_t)b * CIN * NPOS;
#pragma unroll
  for (int i = 0; i < 4; i++) {
    int cc = c0 + ty + i * 8, nn = n0 + tx;
    t[ty + i * 8][tx] = (nn < NPOS) ? xb[(size_t)cc * NPOS + nn] : 0.f;
  }
  __syncthreads();
  u16* Ab = At + (size_t)b * NPOS * CIN;
#pragma unroll
  for (int i = 0; i < 4; i++) {
    int nn = n0 + ty + i * 8, cc = c0 + tx;
    if (nn < NPOS) Ab[(size_t)nn * CIN + cc] = f2bf(t[tx][ty + i * 8]);
  }
}

// ---------------------------------------------------------------------------
// depthwise 3x3 SAME conv + bias + identity residual (fp32)
// ---------------------------------------------------------------------------
__global__ __launch_bounds__(256) void conv_res_k(
    const float* __restrict__ T0, const float* __restrict__ pcw,
    const float* __restrict__ pcb, float* __restrict__ T1)
{
  int idx = blockIdx.x * 256 + threadIdx.x;
  if (idx >= B_ * NPOS * 96) return;
  int d4 = idx % 96; int rem = idx / 96;
  int n = rem % NPOS; int b = rem / NPOS;
  int hh = n / 14, ww = n % 14;
  int d0 = d4 * 4;
  float w9[4][9];
#pragma unroll
  for (int j = 0; j < 4; j++)
#pragma unroll
    for (int t = 0; t < 9; t++) w9[j][t] = pcw[(d0 + j) * 9 + t];
  const float* base = T0 + (size_t)b * NPOS * DM;
  float4 ctr = *(const float4*)(base + (size_t)n * DM + d0);
  float ax = ctr.x + pcb[d0], ay = ctr.y + pcb[d0 + 1];
  float az = ctr.z + pcb[d0 + 2], aw = ctr.w + pcb[d0 + 3];
#pragma unroll
  for (int kh = 0; kh < 3; kh++) {
    int h2 = hh + kh - 1;
    if (h2 < 0 || h2 >= 14) continue;
#pragma unroll
    for (int kw = 0; kw < 3; kw++) {
      int w2 = ww + kw - 1;
      if (w2 < 0 || w2 >= 14) continue;
      float4 v = *(const float4*)(base + (size_t)(h2 * 14 + w2) * DM + d0);
      int t = kh * 3 + kw;
      ax += v.x * w9[0][t]; ay += v.y * w9[1][t];
      az += v.z * w9[2][t]; aw += v.w * w9[3][t];
    }
  }
  float4 o = {ax, ay, az, aw};
  *(float4*)(T1 + (size_t)b * NPOS * DM + (size_t)n * DM + d0) = o;
}

// ---------------------------------------------------------------------------
// LayerNorm(384) f32 -> bf16, one wave per row (float2-vectorized)
// ---------------------------------------------------------------------------
__global__ __launch_bounds__(256) void ln_k(
    const float* __restrict__ in, const float* __restrict__ w,
    const float* __restrict__ bb, u16* __restrict__ out)
{
  int row = blockIdx.x * 4 + (threadIdx.x >> 6);
  int ln = threadIdx.x & 63;
  const float2* r = (const float2*)(in + (size_t)row * DM);
  float2 v[3]; float s = 0.f, sq = 0.f;
#pragma unroll
  for (int j = 0; j < 3; j++) {
    v[j] = r[ln + 64 * j];
    s += v[j].x + v[j].y; sq += v[j].x * v[j].x + v[j].y * v[j].y;
  }
#pragma unroll
  for (int o = 1; o < 64; o <<= 1) { s += __shfl_xor(s, o, 64); sq += __shfl_xor(sq, o, 64); }
  float mu = s * (1.f / 384.f);
  float var = sq * (1.f / 384.f) - mu * mu;
  float rs = rsqrtf(var + 1e-5f);
  uint32_t* orow = (uint32_t*)(out + (size_t)row * DM);
#pragma unroll
  for (int j = 0; j < 3; j++) {
    int d = (ln + 64 * j) * 2;
    float a = (v[j].x - mu) * rs * w[d] + bb[d];
    float bq = (v[j].y - mu) * rs * w[d + 1] + bb[d + 1];
    orow[ln + 64 * j] = (uint32_t)f2bf(a) | ((uint32_t)f2bf(bq) << 16);
  }
}

// ---------------------------------------------------------------------------
// BN1 over (batch, dmodel) per position n: two-stage stats
// ---------------------------------------------------------------------------
__global__ __launch_bounds__(256) void bn1_partial_k(
    const float* __restrict__ T3, float* __restrict__ part)
{
  int n = blockIdx.x >> 3, g = blockIdx.x & 7;
  int tid = threadIdx.x;
  float s = 0.f, sq = 0.f;
  for (int b2 = g * 16; b2 < g * 16 + 16; b2++) {
    const float* p = T3 + ((size_t)b2 * NPOS + n) * DM;
    for (int d = tid; d < DM; d += 256) { float v = p[d]; s += v; sq += v * v; }
  }
#pragma unroll
  for (int o = 1; o < 64; o <<= 1) { s += __shfl_xor(s, o, 64); sq += __shfl_xor(sq, o, 64); }
  __shared__ float ls[4], lq[4];
  int wv = tid >> 6, ln = tid & 63;
  if (ln == 0) { ls[wv] = s; lq[wv] = sq; }
  __syncthreads();
  if (tid == 0) {
    part[blockIdx.x * 2]     = ls[0] + ls[1] + ls[2] + ls[3];
    part[blockIdx.x * 2 + 1] = lq[0] + lq[1] + lq[2] + lq[3];
  }
}

__global__ __launch_bounds__(256) void bn1_finish_k(
    const float* __restrict__ part, const float* __restrict__ bw,
    const float* __restrict__ bbb, float* __restrict__ scaleArr,
    float* __restrict__ shiftArr)
{
  int n = threadIdx.x;
  if (n >= NPOS) return;
  float S = 0.f, Q = 0.f;
#pragma unroll
  for (int g = 0; g < 8; g++) { S += part[(n * 8 + g) * 2]; Q += part[(n * 8 + g) * 2 + 1]; }
  float mu = S / 49152.f;
  float var = Q / 49152.f - mu * mu;
  float rs = rsqrtf(var + 2e-5f);
  float sc = rs * bw[n];
  scaleArr[n] = sc;
  shiftArr[n] = bbb[n] - mu * sc;
}

__global__ __launch_bounds__(256) void bn1_apply_k(
    const float* __restrict__ T3, const float* __restrict__ scaleArr,
    const float* __restrict__ shiftArr, u16* __restrict__ outb)
{
  int idx = blockIdx.x * 256 + threadIdx.x;           // float4 index
  if (idx >= MT * DM / 4) return;
  int n = (idx / 96) % NPOS;
  float4 v = *(const float4*)(T3 + (size_t)idx * 4);
  float sc = scaleArr[n], sh = shiftArr[n];
  uint32_t p0 = (uint32_t)f2bf(v.x * sc + sh) | ((uint32_t)f2bf(v.y * sc + sh) << 16);
  uint32_t p1 = (uint32_t)f2bf(v.z * sc + sh) | ((uint32_t)f2bf(v.w * sc + sh) << 16);
  ((uint2*)outb)[idx] = make_uint2(p0, p1);
}

// ---------------------------------------------------------------------------
// split-K reduce for lin head + bias
// ---------------------------------------------------------------------------
__global__ __launch_bounds__(256) void lin_reduce_k(
    const float* __restrict__ part, const float* __restrict__ lb,
    float* __restrict__ y)
{
  int idx = blockIdx.x * 256 + threadIdx.x;
  if (idx >= 128 * DM) return;
  int col = idx % DM;
  float s = lb[col];
#pragma unroll
  for (int sp = 0; sp < 49; sp++) s += part[(size_t)sp * (128 * DM) + idx];
  y[idx] = s;
}

// ---------------------------------------------------------------------------
// BN2 over batch (128) per feature col, in-place on y
// ---------------------------------------------------------------------------
__global__ __launch_bounds__(64) void bn2_k(
    float* __restrict__ y, const float* __restrict__ w,
    const float* __restrict__ bb)
{
  int col = blockIdx.x; int ln = threadIdx.x;
  float v0 = y[(size_t)ln * DM + col];
  float v1 = y[(size_t)(ln + 64) * DM + col];
  float s = v0 + v1, sq = v0 * v0 + v1 * v1;
#pragma unroll
  for (int o = 1; o < 64; o <<= 1) { s += __shfl_xor(s, o, 64); sq += __shfl_xor(sq, o, 64); }
  float mu = s / 128.f;
  float var = sq / 128.f - mu * mu;
  float rs = rsqrtf(var + 2e-5f);
  float sc = rs * w[col], sh = bb[col] - mu * sc;
  y[(size_t)ln * DM + col] = v0 * sc + sh;
  y[(size_t)(ln + 64) * DM + col] = v1 * sc + sh;
}

// ---------------------------------------------------------------------------
// merged f32 -> bf16 cast for the six small weight matrices
// ---------------------------------------------------------------------------
__global__ __launch_bounds__(256) void castall_k(
    const float* __restrict__ s0, u16* __restrict__ d0,
    const float* __restrict__ s1, u16* __restrict__ d1,
    const float* __restrict__ s2, u16* __restrict__ d2,
    const float* __restrict__ s3, u16* __restrict__ d3,
    const float* __restrict__ s4, u16* __restrict__ d4,
    const float* __restrict__ s5, u16* __restrict__ d5)
{
  const int b0 = 262144, b1 = b0 + 98304, b2 = b1 + 110592,
            b3 = b2 + 36864, b4 = b3 + 147456, b5 = b4 + 147456; // 802816
  int idx = blockIdx.x * 256 + threadIdx.x;
  int stride = gridDim.x * 256;
  for (; idx < b5; idx += stride) {
    const float* s; u16* d; int l;
    if      (idx < b0) { s = s0; d = d0; l = idx; }
    else if (idx < b1) { s = s1; d = d1; l = idx - b0; }
    else if (idx < b2) { s = s2; d = d2; l = idx - b1; }
    else if (idx < b3) { s = s3; d = d3; l = idx - b2; }
    else if (idx < b4) { s = s4; d = d4; l = idx - b3; }
    else               { s = s5; d = d5; l = idx - b4; }
    float4 v = *(const float4*)(s + (size_t)l * 4);
    uint32_t p0 = (uint32_t)f2bf(v.x) | ((uint32_t)f2bf(v.y) << 16);
    uint32_t p1 = (uint32_t)f2bf(v.z) | ((uint32_t)f2bf(v.w) << 16);
    ((uint2*)d)[l] = make_uint2(p0, p1);
  }
}

// ---------------------------------------------------------------------------
// Orchestration
// ---------------------------------------------------------------------------
extern "C" void kernel_launch(void* const* d_in, const int* in_sizes, int n_in,
                              void* d_out, int out_size, void* d_ws, size_t ws_size,
                              hipStream_t stream)
{
  (void)in_sizes; (void)n_in; (void)out_size;
  const float* x    = (const float*)d_in[0];
  const float* fc1w = (const float*)d_in[1];
  const float* fc1b = (const float*)d_in[2];
  const float* fc2w = (const float*)d_in[3];
  const float* fc2b = (const float*)d_in[4];
  const float* pcw  = (const float*)d_in[5];
  const float* pcb  = (const float*)d_in[6];
  const float* ln1w = (const float*)d_in[7];
  const float* ln1b = (const float*)d_in[8];
  const float* qkvw = (const float*)d_in[9];
  const float* rpet = (const float*)d_in[10];
  const float* projw= (const float*)d_in[11];
  const float* projb= (const float*)d_in[12];
  const float* ln2w = (const float*)d_in[13];
  const float* ln2b = (const float*)d_in[14];
  const float* m1w  = (const float*)d_in[15];
  const float* m1b  = (const float*)d_in[16];
  const float* m2w  = (const float*)d_in[17];
  const float* m2b  = (const float*)d_in[18];
  const float* bn1w = (const float*)d_in[19];
  const float* bn1b = (const float*)d_in[20];
  const float* linw = (const float*)d_in[21];
  const float* linb = (const float*)d_in[22];
  const float* bn2w = (const float*)d_in[23];
  const float* bn2b = (const float*)d_in[24];
  float* y = (float*)d_out;

  // -------- aliased workspace layout (regions share by liveness) ----------
  const size_t RA = 0;                      // At / MLP1
  const size_t RB = 77070336;               // U / QKV / T3nb
  const size_t RC = RB + 57802752;          // H / AO / H2
  const size_t RD = RC + 19267584;          // T0 / T2
  const size_t RE = RD + 38535168;          // T1 / T3
  const size_t RF = RE + 38535168;          // PART (lin split-K)
  const size_t RG = RF + 9633792;           // small bf16 weights
  const size_t RS = RG + 6422528;           // bn1 scale/shift + partials + lut
  const size_t NEED = RS + 2048 + 16384 + 45056;
  if (ws_size < NEED) return;

  char* ws = (char*)d_ws;
  u16*   At    = (u16*)(ws + RA);
  u16*   MLP1  = (u16*)(ws + RA);
  u16*   U     = (u16*)(ws + RB);
  u16*   QKV   = (u16*)(ws + RB);
  u16*   T3nb  = (u16*)(ws + RB);
  u16*   H     = (u16*)(ws + RC);
  u16*   AO    = (u16*)(ws + RC);
  u16*   H2    = (u16*)(ws + RC);
  float* T0    = (float*)(ws + RD);
  float* T2    = (float*)(ws + RD);
  float* T1    = (float*)(ws + RE);
  float* T3    = (float*)(ws + RE);
  float* PART  = (float*)(ws + RF);
  u16*   wb_fc1 = (u16*)(ws + RG);
  u16*   wb_fc2 = wb_fc1 + 1048576;
  u16*   wb_qkv = wb_fc2 + 393216;
  u16*   wb_proj= wb_qkv + 442368;
  u16*   wb_m1  = wb_proj + 147456;
  u16*   wb_m2  = wb_m1 + 589824;
  float* bnS   = (float*)(ws + RS);
  float* bnSh  = bnS + 196;
  float* bnP   = (float*)(ws + RS + 2048);
  uint8_t* blut = (uint8_t*)(ws + RS + 2048 + 16384);

  // weight casts (f32 -> bf16), one merged kernel + bucket LUT
  castall_k<<<1024, 256, 0, stream>>>(fc1w, wb_fc1, fc2w, wb_fc2, qkvw, wb_qkv,
                                      projw, wb_proj, m1w, wb_m1, m2w, wb_m2);
  blut_k<<<196, 224, 0, stream>>>(blut);

  // x (B,CIN,N) -> At (B*N, CIN) bf16
  transpose_cast_k<<<dim3(32, 7, 128), dim3(32, 8), 0, stream>>>(x, At);

  // embed fc1: U = relu6(At @ fc1w^T + b)   [25088 x 1024]  — 256² 8-phase
  gemm256_k<<<98 * 4, 512, 0, stream>>>(At, wb_fc1, fc1b, U,
                                        MT, 1024, 1024, 1024, 1024, 4);
  // embed fc2: T0 = U @ fc2w^T + b          [25088 x 384] f32
  gemm_k<1><<<196 * 3, 256, 0, stream>>>(U, wb_fc2, fc2b, nullptr, T0,
                                          MT, 384, 1024, 1024, 1024, 3, 0);
  // depthwise conv + bias + residual -> T1
  conv_res_k<<<(B_ * NPOS * 96 + 255) / 256, 256, 0, stream>>>(T0, pcw, pcb, T1);
  // LN1 -> H (bf16)
  ln_k<<<MT / 4, 256, 0, stream>>>(T1, ln1w, ln1b, H);
  // qkv: QKV = H @ qkvw^T (no bias)          [25088 x 1152] bf16
  gemm_k<2><<<196 * 9, 256, 0, stream>>>(H, wb_qkv, nullptr, nullptr, QKV,
                                          MT, 1152, 384, 384, 384, 9, 0);
  // fused attention (rpe in-kernel, flash-style, LUT bias, 2-tile ILP,
  // K direct from L2, 4 blocks/CU) -> AO
  attn_k<<<1536, 256, 0, stream>>>(QKV, rpet, blut, AO);
  // proj + residual(T1) -> T2 (f32)
  gemm_k<3><<<196 * 3, 256, 0, stream>>>(AO, wb_proj, projb, T1, T2,
                                          MT, 384, 384, 384, 384, 3, 0);
  // LN2 -> H2 (bf16)
  ln_k<<<MT / 4, 256, 0, stream>>>(T2, ln2w, ln2b, H2);
  // mlp fc1: MLP1 = relu6(H2 @ m1w^T + b)    [25088 x 1536] bf16 — 256² 8-phase
  gemm256_k<<<98 * 6, 512, 0, stream>>>(H2, wb_m1, m1b, MLP1,
                                        MT, 1536, 384, 384, 384, 6);
  // mlp fc2 + residual(T2) -> T3 (f32)
  gemm_k<3><<<196 * 3, 256, 0, stream>>>(MLP1, wb_m2, m2b, T2, T3,
                                          MT, 384, 1536, 1536, 1536, 3, 0);
  // BN1 (per position) -> T3nb (bf16)
  bn1_partial_k<<<196 * 8, 256, 0, stream>>>(T3, bnP);
  bn1_finish_k<<<1, 256, 0, stream>>>(bnP, bn1w, bn1b, bnS, bnSh);
  bn1_apply_k<<<(MT * DM / 4 + 255) / 256, 256, 0, stream>>>(T3, bnS, bnSh, T3nb);
  // lin head: y = T3nb(128 x 75264) @ linw^T, split-K 49 x 1536 (W f32 direct)
  gemm_k<4><<<3 * 49, 256, 0, stream>>>(T3nb, linw, nullptr, nullptr, PART,
                                         128, 384, 1536, 75264, 75264, 3, 1536);
  lin_reduce_k<<<192, 256, 0, stream>>>(PART, linb, y);
  // BN2 (per feature over batch), in place on d_out
  bn2_k<<<384, 64, 0, stream>>>(y, bn2w, bn2b);
}